// Round 18
// baseline (911.378 us; speedup 1.0000x reference)
//
#include <hip/hip_runtime.h>
#include <math.h>

namespace {

constexpr int Bsz = 4;
constexpr int L   = 2048;
constexpr int D   = 1024;
constexpr int DI  = 2048;
constexpr int DSTATE = 16;
constexpr int DTR = 64;
constexpr int ML  = Bsz * L; // 8192 rows
constexpr int NCH = 32;      // chunks per sequence
constexpr int CL  = 64;      // chunk length
constexpr float LOG2E = 1.4426950408889634f;

typedef __attribute__((ext_vector_type(8))) short bfrag;   // 8 bf16 (4 VGPRs)
typedef __attribute__((ext_vector_type(4))) float f32x4;

// ---- bf16 bit helpers (RNE) ----
__device__ __forceinline__ unsigned short f2b(float f) {
  union { float f; unsigned int u; } c; c.f = f;
  unsigned int u = c.u;
  unsigned int r = (u + 0x7fffu + ((u >> 16) & 1u)) >> 16;
  return (unsigned short)r;
}
__device__ __forceinline__ float b2f(unsigned short h) {
  union { unsigned int u; float f; } c; c.u = ((unsigned int)h) << 16;
  return c.f;
}
__device__ __forceinline__ float fexp2(float x) {
  return __builtin_amdgcn_exp2f(x);
}

// ---- async global->LDS 16B ----
__device__ __forceinline__ void async16(const void* g, void* l) {
  __builtin_amdgcn_global_load_lds(
      (const __attribute__((address_space(1))) void*)g,
      (__attribute__((address_space(3))) void*)l, 16, 0, 0);
}

// ---------------- activations (HW-fast transcendentals only) ----------------
template<int ACT>
__device__ __forceinline__ float activate(float x) {
  if (ACT == 1) {                       // silu
    return x / (1.f + __expf(-x));
  }
  if (ACT == 2) {                       // gelu (tanh form, max dev ~3e-3)
    const float y = 1.5957691216f * (x + 0.044715f * x * x * x);
    return x / (1.f + __expf(-y));
  }
  if (ACT == 3) {                       // softplus
    return (x > 20.f) ? x : __logf(1.f + __expf(x));
  }
  return x;
}

// ---------------- 256-tile 4-phase counted-vmcnt bf16 MFMA GEMM ----------------
// (round-13 proven; used for in_proj N=4096 and mlp1 N=2048)
template<int ACT, bool HAS_BIAS, int BN, bool SPLIT>
__global__ __launch_bounds__(512) void gemm4(
    const unsigned short* __restrict__ A, long lda,
    const unsigned short* __restrict__ W, long ldw,
    const float* __restrict__ bias,
    unsigned short* __restrict__ C0,
    unsigned short* __restrict__ C1,
    long ldc, int K)
{
  constexpr int NB   = BN / 64;      // n-frags per wave (4 or 2)
  constexpr int ABUF = 256 * 64;     // elems per A buffer
  constexpr int BBUF = BN * 64;
  constexpr int UB   = NB;           // B-unit loads per thread (4 or 2)
  __shared__ unsigned short lds[2 * ABUF + 2 * BBUF];

  const int tid  = threadIdx.x;
  const int lane = tid & 63;
  const int wid  = tid >> 6;
  const int wr   = wid >> 2;         // 0..1
  const int wc   = wid & 3;          // 0..3
  const int frow = lane & 15;
  const int klg  = lane >> 4;

  // chunked n-major XCD swizzle (nwg % 8 == 0 for all our grids)
  const int gy = gridDim.y;
  int id = blockIdx.x * gy + blockIdx.y;          // hw linear (n-major)
  const int q = (gridDim.x * gy) >> 3;
  id = (id & 7) * q + (id >> 3);                  // XCD k -> contiguous chunk
  const int by = id % gy;
  const int bx = id / gy;
  const long bm = (long)by * 256;
  const long bn = (long)bx * BN;

  unsigned short* Cb;
  long cbase;
  if (SPLIT) {
    if (bn < 2048) { Cb = C0; cbase = bn; }
    else           { Cb = C1; cbase = bn - 2048; }
  } else { Cb = C0; cbase = bn; }

  f32x4 acc[8][NB];
  #pragma unroll
  for (int m = 0; m < 8; ++m)
    #pragma unroll
    for (int n = 0; n < NB; ++n)
      acc[m][n] = (f32x4){0.f, 0.f, 0.f, 0.f};

  auto stageB = [&](int kt) {
    const long kcol = (long)kt * 64;
    unsigned short* dst = &lds[2 * ABUF + (kt & 1) * BBUF];
    #pragma unroll
    for (int l = 0; l < UB; ++l) {
      const int idx = tid + l * 512;               // [0, BN*8)
      const int row = idx >> 3;                    // [0, BN)
      const int ch  = (idx & 7) ^ (row & 7);
      async16(W + (bn + row) * ldw + kcol + ch * 8, dst + idx * 8);
    }
  };
  auto stageA = [&](int kt, int mh) {
    const long kcol = (long)kt * 64;
    unsigned short* dst = &lds[(kt & 1) * ABUF];
    #pragma unroll
    for (int l = 0; l < 2; ++l) {
      const int idx = tid + l * 512;               // [0, 1024)
      const int rl  = idx >> 3;                    // [0, 128)
      const int row = mh * 64 + (rl & 63) + (rl >> 6) * 128;
      const int ch  = (idx & 7) ^ (row & 7);
      async16(A + (bm + row) * lda + kcol + ch * 8, dst + row * 64 + (idx & 7) * 8);
    }
  };

  const int NT = K >> 6;
  stageB(0); stageA(0, 0); stageA(0, 1);
  asm volatile("s_waitcnt vmcnt(%0)" :: "n"(2) : "memory");
  __builtin_amdgcn_sched_barrier(0);
  __builtin_amdgcn_s_barrier();

  for (int kt = 0; kt < NT; ++kt) {
    const unsigned short* Ab = &lds[(kt & 1) * ABUF];
    const unsigned short* Bb = &lds[2 * ABUF + (kt & 1) * BBUF];
    const bool pf = (kt + 1 < NT);
    #pragma unroll
    for (int kk = 0; kk < 2; ++kk) {
      bfrag bv[NB], av[4];
      #pragma unroll
      for (int n = 0; n < NB; ++n) {
        const int r = wc * (BN / 4) + n * 16 + frow;
        bv[n] = *reinterpret_cast<const bfrag*>(&Bb[r * 64 + ((kk * 4 + klg) ^ (r & 7)) * 8]);
      }
      #pragma unroll
      for (int m = 0; m < 4; ++m) {
        const int r = wr * 128 + m * 16 + frow;
        av[m] = *reinterpret_cast<const bfrag*>(&Ab[r * 64 + ((kk * 4 + klg) ^ (r & 7)) * 8]);
      }
      if (pf) { if (kk == 0) stageB(kt + 1); else stageA(kt + 1, 1); }
      __builtin_amdgcn_s_setprio(1);
      #pragma unroll
      for (int m = 0; m < 4; ++m)
        #pragma unroll
        for (int n = 0; n < NB; ++n)
          acc[m][n] = __builtin_amdgcn_mfma_f32_16x16x32_bf16(bv[n], av[m], acc[m][n], 0, 0, 0);
      __builtin_amdgcn_s_setprio(0);
      if (kk == 0) {
        asm volatile("s_waitcnt vmcnt(%0)" :: "n"(UB) : "memory");
      }
      __builtin_amdgcn_sched_barrier(0);
      __builtin_amdgcn_s_barrier();
      #pragma unroll
      for (int m = 0; m < 4; ++m) {
        const int r = wr * 128 + 64 + m * 16 + frow;
        av[m] = *reinterpret_cast<const bfrag*>(&Ab[r * 64 + ((kk * 4 + klg) ^ (r & 7)) * 8]);
      }
      if (pf && kk == 0) stageA(kt + 1, 0);
      __builtin_amdgcn_s_setprio(1);
      #pragma unroll
      for (int m = 0; m < 4; ++m)
        #pragma unroll
        for (int n = 0; n < NB; ++n)
          acc[4 + m][n] = __builtin_amdgcn_mfma_f32_16x16x32_bf16(bv[n], av[m], acc[4 + m][n], 0, 0, 0);
      __builtin_amdgcn_s_setprio(0);
      if (kk == 1) {
        if (kt + 1 == NT) break;
        asm volatile("s_waitcnt vmcnt(%0)" :: "n"(2) : "memory");
      }
      __builtin_amdgcn_sched_barrier(0);
      __builtin_amdgcn_s_barrier();
    }
  }

  #pragma unroll
  for (int n = 0; n < NB; ++n) {
    const long coff = wc * (BN / 4) + n * 16 + klg * 4;
    float4 b4 = make_float4(0.f, 0.f, 0.f, 0.f);
    if (HAS_BIAS) b4 = *reinterpret_cast<const float4*>(&bias[bn + coff]);
    #pragma unroll
    for (int m = 0; m < 8; ++m) {
      const long row = bm + wr * 128 + m * 16 + frow;
      const float v0 = activate<ACT>(acc[m][n][0] + b4.x);
      const float v1 = activate<ACT>(acc[m][n][1] + b4.y);
      const float v2 = activate<ACT>(acc[m][n][2] + b4.z);
      const float v3 = activate<ACT>(acc[m][n][3] + b4.w);
      ushort4 o; o.x = f2b(v0); o.y = f2b(v1); o.z = f2b(v2); o.w = f2b(v3);
      *reinterpret_cast<ushort4*>(&Cb[row * ldc + cbase + coff]) = o;
    }
  }
}

// ---------------- 128x256-tile single-barrier bf16 MFMA GEMM (N=1024 ops) ------
// BM=128, BN=256, 512 thr = 8 waves (2M x 4N); per wave 64x64 = 4m x 4n frags
// -> 16 MFMA per kk-phase, 2 phases/tile (double the content per sync of the
// BN=128 path these ops used before). Round-14 flow: issue full stage(t+1)
// first, compute, vmcnt(0), ONE barrier per tile. Same swizzle/epilogue.
template<int ACT, bool HAS_BIAS>
__global__ __launch_bounds__(512) void gemm128(
    const unsigned short* __restrict__ A, long lda,
    const unsigned short* __restrict__ W, long ldw,
    const float* __restrict__ bias,
    unsigned short* __restrict__ C,
    long ldc, int K)
{
  constexpr int ABUF = 128 * 64;     // 16 KB
  constexpr int BBUF = 256 * 64;     // 32 KB
  __shared__ unsigned short lds[2 * ABUF + 2 * BBUF];   // 96 KB

  const int tid  = threadIdx.x;
  const int lane = tid & 63;
  const int wid  = tid >> 6;
  const int wr   = wid >> 2;         // 0..1 (64-row halves)
  const int wc   = wid & 3;          // 0..3 (64-col quarters)
  const int frow = lane & 15;
  const int klg  = lane >> 4;

  // chunked n-major XCD swizzle (nwg % 8 == 0)
  const int gy = gridDim.y;
  int id = blockIdx.x * gy + blockIdx.y;
  const int q = (gridDim.x * gy) >> 3;
  id = (id & 7) * q + (id >> 3);
  const int by = id % gy;
  const int bx = id / gy;
  const long bm = (long)by * 128;
  const long bn = (long)bx * 256;

  f32x4 acc[4][4];
  #pragma unroll
  for (int m = 0; m < 4; ++m)
    #pragma unroll
    for (int n = 0; n < 4; ++n)
      acc[m][n] = (f32x4){0.f, 0.f, 0.f, 0.f};

  auto stage = [&](int kt) {
    const long kcol = (long)kt * 64;
    unsigned short* dA = &lds[(kt & 1) * ABUF];
    #pragma unroll
    for (int l = 0; l < 2; ++l) {                  // A: 2 loads/thread
      const int idx = tid + l * 512;               // [0, 1024)
      const int row = idx >> 3;                    // [0, 128)
      const int ch  = (idx & 7) ^ (row & 7);
      async16(A + (bm + row) * lda + kcol + ch * 8, dA + idx * 8);
    }
    unsigned short* dB = &lds[2 * ABUF + (kt & 1) * BBUF];
    #pragma unroll
    for (int l = 0; l < 4; ++l) {                  // B: 4 loads/thread
      const int idx = tid + l * 512;               // [0, 2048)
      const int row = idx >> 3;                    // [0, 256)
      const int ch  = (idx & 7) ^ (row & 7);
      async16(W + (bn + row) * ldw + kcol + ch * 8, dB + idx * 8);
    }
  };

  const int NT = K >> 6;
  stage(0);
  asm volatile("s_waitcnt vmcnt(0)" ::: "memory");
  __builtin_amdgcn_sched_barrier(0);
  __builtin_amdgcn_s_barrier();

  for (int kt = 0; kt < NT; ++kt) {
    if (kt + 1 < NT) stage(kt + 1);        // issue-early; writes OTHER buffer
    __builtin_amdgcn_sched_barrier(0);
    const unsigned short* Ab = &lds[(kt & 1) * ABUF];
    const unsigned short* Bb = &lds[2 * ABUF + (kt & 1) * BBUF];
    __builtin_amdgcn_s_setprio(1);
    #pragma unroll
    for (int kk = 0; kk < 2; ++kk) {
      bfrag av[4], bv[4];
      #pragma unroll
      for (int m = 0; m < 4; ++m) {
        const int r = wr * 64 + m * 16 + frow;
        av[m] = *reinterpret_cast<const bfrag*>(&Ab[r * 64 + ((kk * 4 + klg) ^ (r & 7)) * 8]);
      }
      #pragma unroll
      for (int n = 0; n < 4; ++n) {
        const int r = wc * 64 + n * 16 + frow;
        bv[n] = *reinterpret_cast<const bfrag*>(&Bb[r * 64 + ((kk * 4 + klg) ^ (r & 7)) * 8]);
      }
      #pragma unroll
      for (int m = 0; m < 4; ++m)
        #pragma unroll
        for (int n = 0; n < 4; ++n)
          acc[m][n] = __builtin_amdgcn_mfma_f32_16x16x32_bf16(bv[n], av[m], acc[m][n], 0, 0, 0);
    }
    __builtin_amdgcn_s_setprio(0);
    if (kt + 1 == NT) break;
    asm volatile("s_waitcnt vmcnt(0)" ::: "memory");
    __builtin_amdgcn_sched_barrier(0);
    __builtin_amdgcn_s_barrier();          // publish buf kt+1 / release buf kt
  }

  // epilogue (swapped mapping): row = ...+frow, cols = ...+klg*4+{0..3}
  #pragma unroll
  for (int n = 0; n < 4; ++n) {
    const long coff = bn + wc * 64 + n * 16 + klg * 4;
    float4 b4 = make_float4(0.f, 0.f, 0.f, 0.f);
    if (HAS_BIAS) b4 = *reinterpret_cast<const float4*>(&bias[coff]);
    #pragma unroll
    for (int m = 0; m < 4; ++m) {
      const long row = bm + wr * 64 + m * 16 + frow;
      const float v0 = activate<ACT>(acc[m][n][0] + b4.x);
      const float v1 = activate<ACT>(acc[m][n][1] + b4.y);
      const float v2 = activate<ACT>(acc[m][n][2] + b4.z);
      const float v3 = activate<ACT>(acc[m][n][3] + b4.w);
      ushort4 o; o.x = f2b(v0); o.y = f2b(v1); o.z = f2b(v2); o.w = f2b(v3);
      *reinterpret_cast<ushort4*>(&C[row * ldc + coff]) = o;
    }
  }
}

// ---------------- 128-tile MFMA GEMM (dt_proj: K=64, write-bound) ----------------
template<int ACT, bool HAS_BIAS>
__global__ __launch_bounds__(256) void gemm_mfma(
    const unsigned short* __restrict__ A, long lda,
    const unsigned short* __restrict__ W, long ldw,
    const float* __restrict__ bias,
    unsigned short* __restrict__ C, long ldc,
    int K)
{
  __shared__ unsigned short As[128 * 32];
  __shared__ unsigned short Bs[128 * 32];
  const int tid  = threadIdx.x;
  const int lane = tid & 63;
  const int w    = tid >> 6;
  const int wr   = w >> 1, wc = w & 1;
  const long bm = (long)blockIdx.y * 128;
  const long bn = (long)blockIdx.x * 128;

  const int srow = tid >> 2;
  const int scol = (tid & 3) * 8;
  const unsigned short* ga0 = A + (bm + srow)      * lda + scol;
  const unsigned short* ga1 = A + (bm + 64 + srow) * lda + scol;
  const unsigned short* gb0 = W + (bn + srow)      * ldw + scol;
  const unsigned short* gb1 = W + (bn + 64 + srow) * ldw + scol;
  char* lA = (char*)As;
  char* lB = (char*)Bs;
  const int loff = tid * 16;

  const int frow = lane & 15;
  const int klg  = lane >> 4;
  const int fko  = klg * 8;

  f32x4 acc[4][4];
  #pragma unroll
  for (int m = 0; m < 4; ++m)
    #pragma unroll
    for (int n = 0; n < 4; ++n)
      acc[m][n] = (f32x4){0.f, 0.f, 0.f, 0.f};

  for (int k0 = 0; k0 < K; k0 += 32) {
    __syncthreads();
    async16(ga0 + k0, lA + loff);
    async16(ga1 + k0, lA + 4096 + loff);
    async16(gb0 + k0, lB + loff);
    async16(gb1 + k0, lB + 4096 + loff);
    __syncthreads();
    bfrag a[4], b[4];
    #pragma unroll
    for (int m = 0; m < 4; ++m)
      a[m] = *reinterpret_cast<const bfrag*>(&As[(wr*64 + m*16 + frow)*32 + fko]);
    #pragma unroll
    for (int n = 0; n < 4; ++n)
      b[n] = *reinterpret_cast<const bfrag*>(&Bs[(wc*64 + n*16 + frow)*32 + fko]);
    #pragma unroll
    for (int m = 0; m < 4; ++m)
      #pragma unroll
      for (int n = 0; n < 4; ++n)
        acc[m][n] = __builtin_amdgcn_mfma_f32_16x16x32_bf16(b[n], a[m], acc[m][n], 0, 0, 0);
  }

  #pragma unroll
  for (int n = 0; n < 4; ++n) {
    const long col = bn + wc*64 + n*16 + klg*4;
    float4 b4 = make_float4(0.f, 0.f, 0.f, 0.f);
    if (HAS_BIAS) b4 = *reinterpret_cast<const float4*>(&bias[col]);
    #pragma unroll
    for (int m = 0; m < 4; ++m) {
      const long row = bm + wr*64 + m*16 + frow;
      const float v0 = activate<ACT>(acc[m][n][0] + b4.x);
      const float v1 = activate<ACT>(acc[m][n][1] + b4.y);
      const float v2 = activate<ACT>(acc[m][n][2] + b4.z);
      const float v3 = activate<ACT>(acc[m][n][3] + b4.w);
      ushort4 o; o.x = f2b(v0); o.y = f2b(v1); o.z = f2b(v2); o.w = f2b(v3);
      *reinterpret_cast<ushort4*>(&C[row * ldc + col]) = o;
    }
  }
}

// ---------------- x_proj MFMA (double-buffered, counted vmcnt) ----------------
__global__ __launch_bounds__(256) void xproj_mfma(
    const unsigned short* __restrict__ A,   // xc (ML x DI)
    const unsigned short* __restrict__ W,   // xp_wb (96 x DI)
    float* __restrict__ xdbl,               // (ML x 96) f32
    unsigned short* __restrict__ dtr)       // (ML x 64) bf16
{
  constexpr int ABUF = 64 * 64;    // 8 KiB
  constexpr int BBUF = 96 * 64;    // 12 KiB
  constexpr int NL   = 5;          // 2 A-loads + 3 B-loads per thread
  __shared__ unsigned short lds[2 * ABUF + 2 * BBUF];  // 40 KiB

  const int tid  = threadIdx.x;
  const int lane = tid & 63;
  const int wv   = tid >> 6;
  const int frow = lane & 15;
  const int klg  = lane >> 4;
  const long bm  = (long)blockIdx.x * 64;

  f32x4 acc[6];
  #pragma unroll
  for (int n = 0; n < 6; ++n) acc[n] = (f32x4){0.f, 0.f, 0.f, 0.f};

  auto stage = [&](int kt, int p) {
    const long kcol = (long)kt * 64;
    #pragma unroll
    for (int l = 0; l < 2; ++l) {
      const int idx = tid + l * 256;
      const int row = idx >> 3;                    // [0, 64)
      const int ch  = (idx & 7) ^ (row & 7);
      async16(A + (bm + row) * DI + kcol + ch * 8,
              &lds[p * ABUF + idx * 8]);
    }
    #pragma unroll
    for (int l = 0; l < 3; ++l) {
      const int idx = tid + l * 256;
      const int row = idx >> 3;                    // [0, 96)
      const int ch  = (idx & 7) ^ (row & 7);
      async16(W + (long)row * DI + kcol + ch * 8,
              &lds[2 * ABUF + p * BBUF + idx * 8]);
    }
  };

  constexpr int NT = DI / 64;   // 32
  stage(0, 0);
  stage(1, 1);
  asm volatile("s_waitcnt vmcnt(%0)" :: "n"(NL) : "memory");
  __builtin_amdgcn_sched_barrier(0);
  __builtin_amdgcn_s_barrier();

  for (int kt = 0; kt < NT; ++kt) {
    const unsigned short* Ab = &lds[(kt & 1) * ABUF];
    const unsigned short* Bb = &lds[2 * ABUF + (kt & 1) * BBUF];
    __builtin_amdgcn_s_setprio(1);
    #pragma unroll
    for (int kk = 0; kk < 2; ++kk) {
      const int ra = wv * 16 + frow;
      const int cha = (kk * 4 + klg) ^ (ra & 7);
      const bfrag a = *reinterpret_cast<const bfrag*>(&Ab[ra * 64 + cha * 8]);
      #pragma unroll
      for (int n = 0; n < 6; ++n) {
        const int rb = n * 16 + frow;
        const int chb = (kk * 4 + klg) ^ (rb & 7);
        const bfrag b = *reinterpret_cast<const bfrag*>(&Bb[rb * 64 + chb * 8]);
        acc[n] = __builtin_amdgcn_mfma_f32_16x16x32_bf16(b, a, acc[n], 0, 0, 0);
      }
    }
    __builtin_amdgcn_s_setprio(0);
    if (kt + 1 == NT) break;
    __builtin_amdgcn_sched_barrier(0);
    __builtin_amdgcn_s_barrier();
    if (kt + 2 < NT) {
      stage(kt + 2, kt & 1);
      asm volatile("s_waitcnt vmcnt(%0)" :: "n"(NL) : "memory");
    } else {
      asm volatile("s_waitcnt vmcnt(0)" ::: "memory");
    }
    __builtin_amdgcn_sched_barrier(0);
    __builtin_amdgcn_s_barrier();
  }

  const long row = bm + wv*16 + frow;
  #pragma unroll
  for (int n = 0; n < 6; ++n) {
    const int col = n*16 + klg*4;
    float4 v; v.x = acc[n][0]; v.y = acc[n][1]; v.z = acc[n][2]; v.w = acc[n][3];
    *reinterpret_cast<float4*>(&xdbl[row * 96 + col]) = v;
    if (n < 4) {
      ushort4 o; o.x = f2b(v.x); o.y = f2b(v.y); o.z = f2b(v.z); o.w = f2b(v.w);
      *reinterpret_cast<ushort4*>(&dtr[row * 64 + col]) = o;
    }
  }
}

// ---------------- fused f32 -> bf16 convert (all 7 segments) ----------------
__global__ __launch_bounds__(256) void cvt_all(
    const float* __restrict__ s0, unsigned short* __restrict__ d0, long n0,
    const float* __restrict__ s1, unsigned short* __restrict__ d1, long n1,
    const float* __restrict__ s2, unsigned short* __restrict__ d2, long n2,
    const float* __restrict__ s3, unsigned short* __restrict__ d3, long n3,
    const float* __restrict__ s4, unsigned short* __restrict__ d4, long n4,
    const float* __restrict__ s5, unsigned short* __restrict__ d5, long n5,
    const float* __restrict__ s6, unsigned short* __restrict__ d6, long n6)
{
  long i = (long)blockIdx.x * 256 + threadIdx.x;
  const float* s; unsigned short* d;
  if      (i < n0)                    { s = s0; d = d0; }
  else if ((i -= n0) < n1)            { s = s1; d = d1; }
  else if ((i -= n1) < n2)            { s = s2; d = d2; }
  else if ((i -= n2) < n3)            { s = s3; d = d3; }
  else if ((i -= n3) < n4)            { s = s4; d = d4; }
  else if ((i -= n4) < n5)            { s = s5; d = d5; }
  else if ((i -= n5) < n6)            { s = s6; d = d6; }
  else return;
  const float4 v = reinterpret_cast<const float4*>(s)[i];
  ushort4 o; o.x = f2b(v.x); o.y = f2b(v.y); o.z = f2b(v.z); o.w = f2b(v.w);
  reinterpret_cast<ushort4*>(d)[i] = o;
}

// ---------------- depthwise causal conv (k=4) + silu, bf16 in/out ----------------
__global__ __launch_bounds__(256) void conv_silu(
    const unsigned short* __restrict__ xin,
    const float* __restrict__ w,     // (DI, 4) f32
    const float* __restrict__ bias,  // (DI) f32
    unsigned short* __restrict__ xc)
{
  const int idx = blockIdx.x * 256 + threadIdx.x;
  const int D4 = DI / 4;
  const int d  = (idx % D4) * 4;
  const int bt = idx / D4;
  const int t  = bt & (L - 1);
  const int b  = bt >> 11;
  const float4 w0 = *reinterpret_cast<const float4*>(w + (long)(d+0)*4);
  const float4 w1 = *reinterpret_cast<const float4*>(w + (long)(d+1)*4);
  const float4 w2 = *reinterpret_cast<const float4*>(w + (long)(d+2)*4);
  const float4 w3 = *reinterpret_cast<const float4*>(w + (long)(d+3)*4);
  const float4 bv = *reinterpret_cast<const float4*>(bias + d);
  float a0 = bv.x, a1 = bv.y, a2 = bv.z, a3 = bv.w;
  const float wk0[4] = {w0.x, w0.y, w0.z, w0.w};
  const float wk1[4] = {w1.x, w1.y, w1.z, w1.w};
  const float wk2[4] = {w2.x, w2.y, w2.z, w2.w};
  const float wk3[4] = {w3.x, w3.y, w3.z, w3.w};
  #pragma unroll
  for (int k = 0; k < 4; ++k) {
    const int tt = t - 3 + k;
    if (tt >= 0) {
      const ushort4 xv = *reinterpret_cast<const ushort4*>(xin + ((long)(b * L + tt)) * DI + d);
      a0 = fmaf(wk0[k], b2f(xv.x), a0);
      a1 = fmaf(wk1[k], b2f(xv.y), a1);
      a2 = fmaf(wk2[k], b2f(xv.z), a2);
      a3 = fmaf(wk3[k], b2f(xv.w), a3);
    }
  }
  a0 = a0 / (1.f + __expf(-a0));
  a1 = a1 / (1.f + __expf(-a1));
  a2 = a2 / (1.f + __expf(-a2));
  a3 = a3 / (1.f + __expf(-a3));
  ushort4 o; o.x = f2b(a0); o.y = f2b(a1); o.z = f2b(a2); o.w = f2b(a3);
  *reinterpret_cast<ushort4*>(xc + (long)bt * DI + d) = o;
}

// ---------------- chunked selective scan (LDS-staged B/C, exp2 decay) ----------
__global__ __launch_bounds__(256) void scan_p1(
    const unsigned short* __restrict__ dt,   // (ML, DI) bf16
    const unsigned short* __restrict__ u,    // (ML, DI) bf16
    const float* __restrict__ xdbl,          // (ML, 96): B at 64
    const float* __restrict__ a_log,         // (DI, 16)
    float* __restrict__ hend,                // (Bsz, NCH, 16, DI)
    float* __restrict__ sdt)                 // (Bsz, NCH, DI)
{
  __shared__ float bcs[CL * 16];             // 4 KB: B rows of the chunk
  const int bid = blockIdx.x;
  const int dg = bid & 7;
  const int c  = (bid >> 3) & (NCH - 1);
  const int b  = bid >> 8;
  const int tid = threadIdx.x;
  const int d  = dg * 256 + tid;
  const long row0 = (long)b * L + (long)c * CL;

  {  // stage B panel: 64 rows x 16 f32 = 256 x async16 (1/thread)
    const int row = tid >> 2, q = tid & 3;
    async16(xdbl + (row0 + row) * 96 + 64 + q * 4, (char*)bcs + tid * 16);
  }

  float A2[16];
  #pragma unroll
  for (int q = 0; q < 4; ++q) {
    const float4 al = *reinterpret_cast<const float4*>(a_log + (long)d * 16 + q * 4);
    A2[q*4+0] = -__expf(al.x) * LOG2E; A2[q*4+1] = -__expf(al.y) * LOG2E;
    A2[q*4+2] = -__expf(al.z) * LOG2E; A2[q*4+3] = -__expf(al.w) * LOG2E;
  }
  float h[16];
  #pragma unroll
  for (int s = 0; s < 16; ++s) h[s] = 0.f;
  float s_dt = 0.f;

  float dtv = b2f(dt[row0 * DI + d]);
  float uv  = b2f(u [row0 * DI + d]);
  asm volatile("s_waitcnt vmcnt(0)" ::: "memory");
  __builtin_amdgcn_sched_barrier(0);
  __syncthreads();                          // B panel ready

  for (int t = 0; t < CL; ++t) {
    float dtn = 0.f, un = 0.f;
    if (t + 1 < CL) {
      const long r2 = row0 + t + 1;
      dtn = b2f(dt[r2 * DI + d]);
      un  = b2f(u [r2 * DI + d]);
    }
    const float* bp = &bcs[t * 16];
    s_dt += dtv;
    const float dtu = dtv * uv;
    #pragma unroll
    for (int s = 0; s < 16; ++s)
      h[s] = fmaf(fexp2(dtv * A2[s]), h[s], dtu * bp[s]);
    dtv = dtn; uv = un;
  }
  const long cb = (long)(b * NCH + c);
  #pragma unroll
  for (int s = 0; s < 16; ++s)
    hend[(cb * 16 + s) * DI + d] = h[s];
  sdt[cb * DI + d] = s_dt;
}

__global__ __launch_bounds__(256) void scan_p2(
    float* __restrict__ hend,
    const float* __restrict__ sdt,
    const float* __restrict__ a_log)
{
  const long idx = (long)blockIdx.x * 256 + threadIdx.x;
  const int d = idx & (DI - 1);
  const int s = (idx >> 11) & 15;
  const int b = idx >> 15;
  const float A2 = -__expf(a_log[(long)d * 16 + s]) * LOG2E;
  float h = 0.f;
  for (int c = 0; c < NCH; ++c) {
    const long cb = (long)(b * NCH + c);
    const long off = (cb * 16 + s) * DI + d;
    const float hl = hend[off];
    const float sd = sdt[cb * DI + d];
    hend[off] = h;
    h = fmaf(fexp2(A2 * sd), h, hl);
  }
}

__global__ __launch_bounds__(256) void scan_p3(
    const unsigned short* __restrict__ dt,
    const unsigned short* __restrict__ u,
    const float* __restrict__ xdbl,          // B at 64, C at 80
    const unsigned short* __restrict__ z,
    const float* __restrict__ a_log,
    const float* __restrict__ dpar,
    const float* __restrict__ hinit,
    unsigned short* __restrict__ y)
{
  __shared__ float bcs[CL * 32];             // 8 KB: B+C rows of the chunk
  const int bid = blockIdx.x;
  const int dg = bid & 7;
  const int c  = (bid >> 3) & (NCH - 1);
  const int b  = bid >> 8;
  const int tid = threadIdx.x;
  const int d  = dg * 256 + tid;
  const long row0 = (long)b * L + (long)c * CL;

  {  // stage B+C panel: 64 rows x 32 f32 = 512 x async16 (2/thread)
    #pragma unroll
    for (int l = 0; l < 2; ++l) {
      const int idx = tid + l * 256;
      const int row = idx >> 3, q = idx & 7;
      async16(xdbl + (row0 + row) * 96 + 64 + q * 4, (char*)bcs + idx * 16);
    }
  }

  float A2[16];
  #pragma unroll
  for (int q = 0; q < 4; ++q) {
    const float4 al = *reinterpret_cast<const float4*>(a_log + (long)d * 16 + q * 4);
    A2[q*4+0] = -__expf(al.x) * LOG2E; A2[q*4+1] = -__expf(al.y) * LOG2E;
    A2[q*4+2] = -__expf(al.z) * LOG2E; A2[q*4+3] = -__expf(al.w) * LOG2E;
  }
  const float Dv = dpar[d];
  const long cb = (long)(b * NCH + c);
  float h[16];
  #pragma unroll
  for (int s = 0; s < 16; ++s)
    h[s] = hinit[(cb * 16 + s) * DI + d];

  float dtv = b2f(dt[row0 * DI + d]);
  float uv  = b2f(u [row0 * DI + d]);
  float zv  = b2f(z [row0 * DI + d]);
  asm volatile("s_waitcnt vmcnt(0)" ::: "memory");
  __builtin_amdgcn_sched_barrier(0);
  __syncthreads();                          // B/C panel ready

  for (int t = 0; t < CL; ++t) {
    float dtn = 0.f, un = 0.f, zn = 0.f;
    if (t + 1 < CL) {
      const long r2 = row0 + t + 1;
      dtn = b2f(dt[r2 * DI + d]);
      un  = b2f(u [r2 * DI + d]);
      zn  = b2f(z [r2 * DI + d]);
    }
    const float* bp = &bcs[t * 32];          // B at +0, C at +16
    const float dtu = dtv * uv;
    float yv = 0.f;
    #pragma unroll
    for (int s = 0; s < 16; ++s) {
      h[s] = fmaf(fexp2(dtv * A2[s]), h[s], dtu * bp[s]);
      yv = fmaf(h[s], bp[16 + s], yv);
    }
    const float sg = zv / (1.f + __expf(-zv));
    y[(row0 + t) * DI + d] = f2b(fmaf(uv, Dv, yv) * sg);
    dtv = dtn; uv = un; zv = zn;
  }
}

// ---------------- fused add-residual + rmsnorm (bf16 chain) ----------------
template<bool RES_F32, bool WRITE_BF, bool WRITE_F32>
__global__ __launch_bounds__(256) void add_rmsnorm(
    const unsigned short* __restrict__ xin,
    const void* __restrict__ resp,
    const float* __restrict__ w,
    unsigned short* __restrict__ out_bf,
    float* __restrict__ out_f32)
{
  const int row = blockIdx.x;
  const int tid = threadIdx.x;
  const long base = (long)row * D;
  const ushort4 t = *reinterpret_cast<const ushort4*>(xin + base + tid * 4);
  float4 v;
  v.x = b2f(t.x); v.y = b2f(t.y); v.z = b2f(t.z); v.w = b2f(t.w);
  if (RES_F32) {
    const float4 r = *reinterpret_cast<const float4*>((const float*)resp + base + tid * 4);
    v.x += r.x; v.y += r.y; v.z += r.z; v.w += r.w;
  } else {
    const ushort4 rb = *reinterpret_cast<const ushort4*>((const unsigned short*)resp + base + tid * 4);
    v.x += b2f(rb.x); v.y += b2f(rb.y); v.z += b2f(rb.z); v.w += b2f(rb.w);
  }
  float ss = v.x*v.x + v.y*v.y + v.z*v.z + v.w*v.w;
  #pragma unroll
  for (int m = 1; m < 64; m <<= 1) ss += __shfl_xor(ss, m);
  __shared__ float red[4];
  if ((tid & 63) == 0) red[tid >> 6] = ss;
  __syncthreads();
  const float tot = red[0] + red[1] + red[2] + red[3];
  const float scale = rsqrtf(tot * (1.f / (float)D) + 1.1920929e-07f);
  const float4 wv = *reinterpret_cast<const float4*>(w + tid * 4);
  float4 o;
  o.x = v.x * scale * wv.x;
  o.y = v.y * scale * wv.y;
  o.z = v.z * scale * wv.z;
  o.w = v.w * scale * wv.w;
  if (WRITE_BF) {
    ushort4 ob; ob.x = f2b(o.x); ob.y = f2b(o.y); ob.z = f2b(o.z); ob.w = f2b(o.w);
    *reinterpret_cast<ushort4*>(out_bf + base + tid * 4) = ob;
  }
  if (WRITE_F32)
    *reinterpret_cast<float4*>(out_f32 + base + tid * 4) = o;
}

} // namespace

extern "C" void kernel_launch(void* const* d_in, const int* in_sizes, int n_in,
                              void* d_out, int out_size, void* d_ws, size_t ws_size,
                              hipStream_t stream)
{
  const float* x0     = (const float*)d_in[0];
  const float* in_w   = (const float*)d_in[1];
  const float* conv_w = (const float*)d_in[2];
  const float* conv_b = (const float*)d_in[3];
  const float* xp_w   = (const float*)d_in[4];
  const float* dtp_w  = (const float*)d_in[5];
  const float* dtp_b  = (const float*)d_in[6];
  const float* a_log  = (const float*)d_in[7];
  const float* d_par  = (const float*)d_in[8];
  const float* out_w  = (const float*)d_in[9];
  const float* w1     = (const float*)d_in[10];
  const float* b1     = (const float*)d_in[11];
  const float* w2     = (const float*)d_in[12];
  const float* b2     = (const float*)d_in[13];
  const float* ln_w   = (const float*)d_in[14];
  const float* ln2_w  = (const float*)d_in[15];
  float* out = (float*)d_out;

  // ---- workspace layout (~216 MiB total) ----
  char* ws = (char*)d_ws;
  unsigned short* in_wb  = (unsigned short*)(ws);                 // 16 Mi
  unsigned short* out_wb = (unsigned short*)(ws + (16UL  << 20)); //  8 Mi
  unsigned short* w1b    = (unsigned short*)(ws + (24UL  << 20)); //  4 Mi
  unsigned short* w2b    = (unsigned short*)(ws + (28UL  << 20)); //  4 Mi
  unsigned short* xbf    = (unsigned short*)(ws + (32UL  << 20)); // 16 Mi: x chain (bf16)
  unsigned short* zb     = (unsigned short*)(ws + (48UL  << 20)); // 32 Mi
  unsigned short* xc     = (unsigned short*)(ws + (80UL  << 20)); // 32 Mi
  float*          xdbl   = (float*)(ws + (112UL << 20));          //  3 Mi
  float*          sdtb   = (float*)(ws + (115UL << 20));          //  1 Mi
  float*          hendb  = (float*)(ws + (116UL << 20));          // 16 Mi
  unsigned short* xinb   = (unsigned short*)(ws + (132UL << 20)); // 32 Mi (alias: dt)
  unsigned short* dtb    = xinb;
  unsigned short* ybf    = (unsigned short*)(ws + (164UL << 20)); // 32 Mi (alias: hm)
  unsigned short* hm     = ybf;
  unsigned short* mo     = (unsigned short*)(ws + (196UL << 20)); // 16 Mi (alias: t2)
  unsigned short* t2     = mo;
  unsigned short* xp_wb  = (unsigned short*)(ws + (212UL << 20)); // 0.75 Mi
  unsigned short* dtp_wb = (unsigned short*)(ws + (213UL << 20)); // 0.5 Mi
  unsigned short* dtrb   = (unsigned short*)(ws + (214UL << 20)); // 1 Mi: (ML,64) bf16

  const dim3 blk(256);
  const dim3 blk5(512);

  // one fused f32 -> bf16 conversion (weights + layer-0 input)
  {
    const long n0 = 2L*2*DI*D/4, n1 = 2L*D*DI/4, n2 = 2L*D*D/4, n3 = 2L*D*D/4;
    const long n4 = 2L*96*DI/4,  n5 = 2L*DI*DTR/4, n6 = (long)ML*D/4;
    const long tot = n0+n1+n2+n3+n4+n5+n6;
    cvt_all<<<dim3((tot + 255)/256), blk, 0, stream>>>(
        in_w, in_wb, n0,  out_w, out_wb, n1,  w1, w1b, n2,  w2, w2b, n3,
        xp_w, xp_wb, n4,  dtp_w, dtp_wb, n5,  x0, xbf, n6);
  }

  for (int layer = 0; layer < 2; ++layer) {
    const long lo = (long)layer;
    const unsigned short* Winb = in_wb + lo * 2 * DI * D;
    // 1. [x_in | z] = x @ in_proj^T  (4-phase 256-tile, N=4096, K=1024, split)
    gemm4<0,false,256,true><<<dim3(16, 32), blk5, 0, stream>>>(
        xbf, D, Winb, D, nullptr, xinb, zb, DI, D);
    // 2. xc = silu(causal_conv(x_in))
    conv_silu<<<dim3((long)ML*DI/4/256), blk, 0, stream>>>(
        xinb, conv_w + lo*DI*4, conv_b + lo*DI, xc);
    // 3. xdbl = xc @ x_proj^T  (dbuf MFMA, N=96, K=2048) + bf16 dt cols
    xproj_mfma<<<dim3(ML/64), blk, 0, stream>>>(
        xc, xp_wb + lo*96*DI, xdbl, dtrb);
    // 4. dt = softplus(dtr @ dt_proj^T + b)  (MFMA 128-tile, N=2048, K=64)
    gemm_mfma<3,true><<<dim3(DI/128, ML/128), blk, 0, stream>>>(
        dtrb, DTR, dtp_wb + lo*DI*DTR, DTR, dtp_b + lo*DI, dtb, DI, DTR);
    // 5. chunked selective scan -> ybf bf16
    scan_p1<<<dim3(Bsz*NCH*(DI/256)), blk, 0, stream>>>(
        dtb, xc, xdbl, a_log + lo*DI*DSTATE, hendb, sdtb);
    scan_p2<<<dim3(Bsz*DSTATE*DI/256), blk, 0, stream>>>(
        hendb, sdtb, a_log + lo*DI*DSTATE);
    scan_p3<<<dim3(Bsz*NCH*(DI/256)), blk, 0, stream>>>(
        dtb, xc, xdbl, zb, a_log + lo*DI*DSTATE, d_par + lo*DI, hendb, ybf);
    // 6. mo = y @ out_proj^T  (128x256 2-phase, N=1024, K=2048)
    gemm128<0,false><<<dim3(4, 64), blk5, 0, stream>>>(
        ybf, DI, out_wb + lo*D*DI, DI, nullptr, mo, D, DI);
    // 7. hm = gelu(mo @ w1^T + b1)  (4-phase 256-tile, N=2048, K=1024)
    gemm4<2,true,256,false><<<dim3(8, 32), blk5, 0, stream>>>(
        mo, D, w1b, D, b1, hm, nullptr, 2*D, D);
    // 8. t2 = gelu(hm @ w2^T + b2)  (128x256 2-phase, N=1024, K=2048)
    gemm128<2,true><<<dim3(4, 64), blk5, 0, stream>>>(
        hm, 2*D, w2b, 2*D, b2, t2, D, 2*D);
    // 9. x = rmsnorm(t2 + x) -> xbf (bf16, in-place residual chain)
    add_rmsnorm<false,true,false><<<dim3(ML), blk, 0, stream>>>(
        t2, xbf, ln_w, xbf, nullptr);
  }
  // final: out = rmsnorm(x + x0)  (f32 residual, f32 output)
  add_rmsnorm<true,false,true><<<dim3(ML), blk, 0, stream>>>(
      xbf, x0, ln2_w, nullptr, out);
}

// Round 19
// 905.320 us; speedup vs baseline: 1.0067x; 1.0067x over previous
//
#include <hip/hip_runtime.h>
#include <math.h>

namespace {

constexpr int Bsz = 4;
constexpr int L   = 2048;
constexpr int D   = 1024;
constexpr int DI  = 2048;
constexpr int DSTATE = 16;
constexpr int DTR = 64;
constexpr int ML  = Bsz * L; // 8192 rows
constexpr int NCH = 64;      // chunks per sequence (r19: doubled for TLP)
constexpr int CL  = 32;      // chunk length
constexpr float LOG2E = 1.4426950408889634f;

typedef __attribute__((ext_vector_type(8))) short bfrag;   // 8 bf16 (4 VGPRs)
typedef __attribute__((ext_vector_type(4))) float f32x4;

// ---- bf16 bit helpers (RNE) ----
__device__ __forceinline__ unsigned short f2b(float f) {
  union { float f; unsigned int u; } c; c.f = f;
  unsigned int u = c.u;
  unsigned int r = (u + 0x7fffu + ((u >> 16) & 1u)) >> 16;
  return (unsigned short)r;
}
__device__ __forceinline__ float b2f(unsigned short h) {
  union { unsigned int u; float f; } c; c.u = ((unsigned int)h) << 16;
  return c.f;
}
__device__ __forceinline__ float fexp2(float x) {
  return __builtin_amdgcn_exp2f(x);
}

// ---- async global->LDS 16B ----
__device__ __forceinline__ void async16(const void* g, void* l) {
  __builtin_amdgcn_global_load_lds(
      (const __attribute__((address_space(1))) void*)g,
      (__attribute__((address_space(3))) void*)l, 16, 0, 0);
}

// ---------------- activations (HW-fast transcendentals only) ----------------
template<int ACT>
__device__ __forceinline__ float activate(float x) {
  if (ACT == 1) {                       // silu
    return x / (1.f + __expf(-x));
  }
  if (ACT == 2) {                       // gelu (tanh form, max dev ~3e-3)
    const float y = 1.5957691216f * (x + 0.044715f * x * x * x);
    return x / (1.f + __expf(-y));
  }
  if (ACT == 3) {                       // softplus
    return (x > 20.f) ? x : __logf(1.f + __expf(x));
  }
  return x;
}

// ---------------- 256-tile 4-phase counted-vmcnt bf16 MFMA GEMM ----------------
template<int ACT, bool HAS_BIAS, int BN, bool SPLIT>
__global__ __launch_bounds__(512) void gemm4(
    const unsigned short* __restrict__ A, long lda,
    const unsigned short* __restrict__ W, long ldw,
    const float* __restrict__ bias,
    unsigned short* __restrict__ C0,
    unsigned short* __restrict__ C1,
    long ldc, int K)
{
  constexpr int NB   = BN / 64;      // n-frags per wave (4 or 2)
  constexpr int ABUF = 256 * 64;     // elems per A buffer
  constexpr int BBUF = BN * 64;
  constexpr int UB   = NB;           // B-unit loads per thread (4 or 2)
  __shared__ unsigned short lds[2 * ABUF + 2 * BBUF];

  const int tid  = threadIdx.x;
  const int lane = tid & 63;
  const int wid  = tid >> 6;
  const int wr   = wid >> 2;         // 0..1
  const int wc   = wid & 3;          // 0..3
  const int frow = lane & 15;
  const int klg  = lane >> 4;

  // chunked n-major XCD swizzle (nwg % 8 == 0 for all our grids)
  const int gy = gridDim.y;
  int id = blockIdx.x * gy + blockIdx.y;          // hw linear (n-major)
  const int q = (gridDim.x * gy) >> 3;
  id = (id & 7) * q + (id >> 3);                  // XCD k -> contiguous chunk
  const int by = id % gy;
  const int bx = id / gy;
  const long bm = (long)by * 256;
  const long bn = (long)bx * BN;

  unsigned short* Cb;
  long cbase;
  if (SPLIT) {
    if (bn < 2048) { Cb = C0; cbase = bn; }
    else           { Cb = C1; cbase = bn - 2048; }
  } else { Cb = C0; cbase = bn; }

  f32x4 acc[8][NB];
  #pragma unroll
  for (int m = 0; m < 8; ++m)
    #pragma unroll
    for (int n = 0; n < NB; ++n)
      acc[m][n] = (f32x4){0.f, 0.f, 0.f, 0.f};

  auto stageB = [&](int kt) {
    const long kcol = (long)kt * 64;
    unsigned short* dst = &lds[2 * ABUF + (kt & 1) * BBUF];
    #pragma unroll
    for (int l = 0; l < UB; ++l) {
      const int idx = tid + l * 512;               // [0, BN*8)
      const int row = idx >> 3;                    // [0, BN)
      const int ch  = (idx & 7) ^ (row & 7);
      async16(W + (bn + row) * ldw + kcol + ch * 8, dst + idx * 8);
    }
  };
  auto stageA = [&](int kt, int mh) {
    const long kcol = (long)kt * 64;
    unsigned short* dst = &lds[(kt & 1) * ABUF];
    #pragma unroll
    for (int l = 0; l < 2; ++l) {
      const int idx = tid + l * 512;               // [0, 1024)
      const int rl  = idx >> 3;                    // [0, 128)
      const int row = mh * 64 + (rl & 63) + (rl >> 6) * 128;
      const int ch  = (idx & 7) ^ (row & 7);
      async16(A + (bm + row) * lda + kcol + ch * 8, dst + row * 64 + (idx & 7) * 8);
    }
  };

  const int NT = K >> 6;
  stageB(0); stageA(0, 0); stageA(0, 1);
  asm volatile("s_waitcnt vmcnt(%0)" :: "n"(2) : "memory");
  __builtin_amdgcn_sched_barrier(0);
  __builtin_amdgcn_s_barrier();

  for (int kt = 0; kt < NT; ++kt) {
    const unsigned short* Ab = &lds[(kt & 1) * ABUF];
    const unsigned short* Bb = &lds[2 * ABUF + (kt & 1) * BBUF];
    const bool pf = (kt + 1 < NT);
    #pragma unroll
    for (int kk = 0; kk < 2; ++kk) {
      bfrag bv[NB], av[4];
      #pragma unroll
      for (int n = 0; n < NB; ++n) {
        const int r = wc * (BN / 4) + n * 16 + frow;
        bv[n] = *reinterpret_cast<const bfrag*>(&Bb[r * 64 + ((kk * 4 + klg) ^ (r & 7)) * 8]);
      }
      #pragma unroll
      for (int m = 0; m < 4; ++m) {
        const int r = wr * 128 + m * 16 + frow;
        av[m] = *reinterpret_cast<const bfrag*>(&Ab[r * 64 + ((kk * 4 + klg) ^ (r & 7)) * 8]);
      }
      if (pf) { if (kk == 0) stageB(kt + 1); else stageA(kt + 1, 1); }
      __builtin_amdgcn_s_setprio(1);
      #pragma unroll
      for (int m = 0; m < 4; ++m)
        #pragma unroll
        for (int n = 0; n < NB; ++n)
          acc[m][n] = __builtin_amdgcn_mfma_f32_16x16x32_bf16(bv[n], av[m], acc[m][n], 0, 0, 0);
      __builtin_amdgcn_s_setprio(0);
      if (kk == 0) {
        asm volatile("s_waitcnt vmcnt(%0)" :: "n"(UB) : "memory");
      }
      __builtin_amdgcn_sched_barrier(0);
      __builtin_amdgcn_s_barrier();
      #pragma unroll
      for (int m = 0; m < 4; ++m) {
        const int r = wr * 128 + 64 + m * 16 + frow;
        av[m] = *reinterpret_cast<const bfrag*>(&Ab[r * 64 + ((kk * 4 + klg) ^ (r & 7)) * 8]);
      }
      if (pf && kk == 0) stageA(kt + 1, 0);
      __builtin_amdgcn_s_setprio(1);
      #pragma unroll
      for (int m = 0; m < 4; ++m)
        #pragma unroll
        for (int n = 0; n < NB; ++n)
          acc[4 + m][n] = __builtin_amdgcn_mfma_f32_16x16x32_bf16(bv[n], av[m], acc[4 + m][n], 0, 0, 0);
      __builtin_amdgcn_s_setprio(0);
      if (kk == 1) {
        if (kt + 1 == NT) break;
        asm volatile("s_waitcnt vmcnt(%0)" :: "n"(2) : "memory");
      }
      __builtin_amdgcn_sched_barrier(0);
      __builtin_amdgcn_s_barrier();
    }
  }

  #pragma unroll
  for (int n = 0; n < NB; ++n) {
    const long coff = wc * (BN / 4) + n * 16 + klg * 4;
    float4 b4 = make_float4(0.f, 0.f, 0.f, 0.f);
    if (HAS_BIAS) b4 = *reinterpret_cast<const float4*>(&bias[bn + coff]);
    #pragma unroll
    for (int m = 0; m < 8; ++m) {
      const long row = bm + wr * 128 + m * 16 + frow;
      const float v0 = activate<ACT>(acc[m][n][0] + b4.x);
      const float v1 = activate<ACT>(acc[m][n][1] + b4.y);
      const float v2 = activate<ACT>(acc[m][n][2] + b4.z);
      const float v3 = activate<ACT>(acc[m][n][3] + b4.w);
      ushort4 o; o.x = f2b(v0); o.y = f2b(v1); o.z = f2b(v2); o.w = f2b(v3);
      *reinterpret_cast<ushort4*>(&Cb[row * ldc + cbase + coff]) = o;
    }
  }
}

// ---------------- 128x256-tile single-barrier bf16 MFMA GEMM (N=1024 ops) ------
template<int ACT, bool HAS_BIAS>
__global__ __launch_bounds__(512) void gemm128(
    const unsigned short* __restrict__ A, long lda,
    const unsigned short* __restrict__ W, long ldw,
    const float* __restrict__ bias,
    unsigned short* __restrict__ C,
    long ldc, int K)
{
  constexpr int ABUF = 128 * 64;     // 16 KB
  constexpr int BBUF = 256 * 64;     // 32 KB
  __shared__ unsigned short lds[2 * ABUF + 2 * BBUF];   // 96 KB

  const int tid  = threadIdx.x;
  const int lane = tid & 63;
  const int wid  = tid >> 6;
  const int wr   = wid >> 2;         // 0..1 (64-row halves)
  const int wc   = wid & 3;          // 0..3 (64-col quarters)
  const int frow = lane & 15;
  const int klg  = lane >> 4;

  const int gy = gridDim.y;
  int id = blockIdx.x * gy + blockIdx.y;
  const int q = (gridDim.x * gy) >> 3;
  id = (id & 7) * q + (id >> 3);
  const int by = id % gy;
  const int bx = id / gy;
  const long bm = (long)by * 128;
  const long bn = (long)bx * 256;

  f32x4 acc[4][4];
  #pragma unroll
  for (int m = 0; m < 4; ++m)
    #pragma unroll
    for (int n = 0; n < 4; ++n)
      acc[m][n] = (f32x4){0.f, 0.f, 0.f, 0.f};

  auto stage = [&](int kt) {
    const long kcol = (long)kt * 64;
    unsigned short* dA = &lds[(kt & 1) * ABUF];
    #pragma unroll
    for (int l = 0; l < 2; ++l) {
      const int idx = tid + l * 512;               // [0, 1024)
      const int row = idx >> 3;                    // [0, 128)
      const int ch  = (idx & 7) ^ (row & 7);
      async16(A + (bm + row) * lda + kcol + ch * 8, dA + idx * 8);
    }
    unsigned short* dB = &lds[2 * ABUF + (kt & 1) * BBUF];
    #pragma unroll
    for (int l = 0; l < 4; ++l) {
      const int idx = tid + l * 512;               // [0, 2048)
      const int row = idx >> 3;                    // [0, 256)
      const int ch  = (idx & 7) ^ (row & 7);
      async16(W + (bn + row) * ldw + kcol + ch * 8, dB + idx * 8);
    }
  };

  const int NT = K >> 6;
  stage(0);
  asm volatile("s_waitcnt vmcnt(0)" ::: "memory");
  __builtin_amdgcn_sched_barrier(0);
  __builtin_amdgcn_s_barrier();

  for (int kt = 0; kt < NT; ++kt) {
    if (kt + 1 < NT) stage(kt + 1);
    __builtin_amdgcn_sched_barrier(0);
    const unsigned short* Ab = &lds[(kt & 1) * ABUF];
    const unsigned short* Bb = &lds[2 * ABUF + (kt & 1) * BBUF];
    __builtin_amdgcn_s_setprio(1);
    #pragma unroll
    for (int kk = 0; kk < 2; ++kk) {
      bfrag av[4], bv[4];
      #pragma unroll
      for (int m = 0; m < 4; ++m) {
        const int r = wr * 64 + m * 16 + frow;
        av[m] = *reinterpret_cast<const bfrag*>(&Ab[r * 64 + ((kk * 4 + klg) ^ (r & 7)) * 8]);
      }
      #pragma unroll
      for (int n = 0; n < 4; ++n) {
        const int r = wc * 64 + n * 16 + frow;
        bv[n] = *reinterpret_cast<const bfrag*>(&Bb[r * 64 + ((kk * 4 + klg) ^ (r & 7)) * 8]);
      }
      #pragma unroll
      for (int m = 0; m < 4; ++m)
        #pragma unroll
        for (int n = 0; n < 4; ++n)
          acc[m][n] = __builtin_amdgcn_mfma_f32_16x16x32_bf16(bv[n], av[m], acc[m][n], 0, 0, 0);
    }
    __builtin_amdgcn_s_setprio(0);
    if (kt + 1 == NT) break;
    asm volatile("s_waitcnt vmcnt(0)" ::: "memory");
    __builtin_amdgcn_sched_barrier(0);
    __builtin_amdgcn_s_barrier();
  }

  #pragma unroll
  for (int n = 0; n < 4; ++n) {
    const long coff = bn + wc * 64 + n * 16 + klg * 4;
    float4 b4 = make_float4(0.f, 0.f, 0.f, 0.f);
    if (HAS_BIAS) b4 = *reinterpret_cast<const float4*>(&bias[coff]);
    #pragma unroll
    for (int m = 0; m < 4; ++m) {
      const long row = bm + wr * 64 + m * 16 + frow;
      const float v0 = activate<ACT>(acc[m][n][0] + b4.x);
      const float v1 = activate<ACT>(acc[m][n][1] + b4.y);
      const float v2 = activate<ACT>(acc[m][n][2] + b4.z);
      const float v3 = activate<ACT>(acc[m][n][3] + b4.w);
      ushort4 o; o.x = f2b(v0); o.y = f2b(v1); o.z = f2b(v2); o.w = f2b(v3);
      *reinterpret_cast<ushort4*>(&C[row * ldc + coff]) = o;
    }
  }
}

// ---------------- 128-tile MFMA GEMM (dt_proj: K=64, write-bound) ----------------
template<int ACT, bool HAS_BIAS>
__global__ __launch_bounds__(256) void gemm_mfma(
    const unsigned short* __restrict__ A, long lda,
    const unsigned short* __restrict__ W, long ldw,
    const float* __restrict__ bias,
    unsigned short* __restrict__ C, long ldc,
    int K)
{
  __shared__ unsigned short As[128 * 32];
  __shared__ unsigned short Bs[128 * 32];
  const int tid  = threadIdx.x;
  const int lane = tid & 63;
  const int w    = tid >> 6;
  const int wr   = w >> 1, wc = w & 1;
  const long bm = (long)blockIdx.y * 128;
  const long bn = (long)blockIdx.x * 128;

  const int srow = tid >> 2;
  const int scol = (tid & 3) * 8;
  const unsigned short* ga0 = A + (bm + srow)      * lda + scol;
  const unsigned short* ga1 = A + (bm + 64 + srow) * lda + scol;
  const unsigned short* gb0 = W + (bn + srow)      * ldw + scol;
  const unsigned short* gb1 = W + (bn + 64 + srow) * ldw + scol;
  char* lA = (char*)As;
  char* lB = (char*)Bs;
  const int loff = tid * 16;

  const int frow = lane & 15;
  const int klg  = lane >> 4;
  const int fko  = klg * 8;

  f32x4 acc[4][4];
  #pragma unroll
  for (int m = 0; m < 4; ++m)
    #pragma unroll
    for (int n = 0; n < 4; ++n)
      acc[m][n] = (f32x4){0.f, 0.f, 0.f, 0.f};

  for (int k0 = 0; k0 < K; k0 += 32) {
    __syncthreads();
    async16(ga0 + k0, lA + loff);
    async16(ga1 + k0, lA + 4096 + loff);
    async16(gb0 + k0, lB + loff);
    async16(gb1 + k0, lB + 4096 + loff);
    __syncthreads();
    bfrag a[4], b[4];
    #pragma unroll
    for (int m = 0; m < 4; ++m)
      a[m] = *reinterpret_cast<const bfrag*>(&As[(wr*64 + m*16 + frow)*32 + fko]);
    #pragma unroll
    for (int n = 0; n < 4; ++n)
      b[n] = *reinterpret_cast<const bfrag*>(&Bs[(wc*64 + n*16 + frow)*32 + fko]);
    #pragma unroll
    for (int m = 0; m < 4; ++m)
      #pragma unroll
      for (int n = 0; n < 4; ++n)
        acc[m][n] = __builtin_amdgcn_mfma_f32_16x16x32_bf16(b[n], a[m], acc[m][n], 0, 0, 0);
  }

  #pragma unroll
  for (int n = 0; n < 4; ++n) {
    const long col = bn + wc*64 + n*16 + klg*4;
    float4 b4 = make_float4(0.f, 0.f, 0.f, 0.f);
    if (HAS_BIAS) b4 = *reinterpret_cast<const float4*>(&bias[col]);
    #pragma unroll
    for (int m = 0; m < 4; ++m) {
      const long row = bm + wr*64 + m*16 + frow;
      const float v0 = activate<ACT>(acc[m][n][0] + b4.x);
      const float v1 = activate<ACT>(acc[m][n][1] + b4.y);
      const float v2 = activate<ACT>(acc[m][n][2] + b4.z);
      const float v3 = activate<ACT>(acc[m][n][3] + b4.w);
      ushort4 o; o.x = f2b(v0); o.y = f2b(v1); o.z = f2b(v2); o.w = f2b(v3);
      *reinterpret_cast<ushort4*>(&C[row * ldc + col]) = o;
    }
  }
}

// ---------------- x_proj MFMA (double-buffered, counted vmcnt) ----------------
__global__ __launch_bounds__(256) void xproj_mfma(
    const unsigned short* __restrict__ A,   // xc (ML x DI)
    const unsigned short* __restrict__ W,   // xp_wb (96 x DI)
    float* __restrict__ xdbl,               // (ML x 96) f32
    unsigned short* __restrict__ dtr)       // (ML x 64) bf16
{
  constexpr int ABUF = 64 * 64;    // 8 KiB
  constexpr int BBUF = 96 * 64;    // 12 KiB
  constexpr int NL   = 5;          // 2 A-loads + 3 B-loads per thread
  __shared__ unsigned short lds[2 * ABUF + 2 * BBUF];  // 40 KiB

  const int tid  = threadIdx.x;
  const int lane = tid & 63;
  const int wv   = tid >> 6;
  const int frow = lane & 15;
  const int klg  = lane >> 4;
  const long bm  = (long)blockIdx.x * 64;

  f32x4 acc[6];
  #pragma unroll
  for (int n = 0; n < 6; ++n) acc[n] = (f32x4){0.f, 0.f, 0.f, 0.f};

  auto stage = [&](int kt, int p) {
    const long kcol = (long)kt * 64;
    #pragma unroll
    for (int l = 0; l < 2; ++l) {
      const int idx = tid + l * 256;
      const int row = idx >> 3;                    // [0, 64)
      const int ch  = (idx & 7) ^ (row & 7);
      async16(A + (bm + row) * DI + kcol + ch * 8,
              &lds[p * ABUF + idx * 8]);
    }
    #pragma unroll
    for (int l = 0; l < 3; ++l) {
      const int idx = tid + l * 256;
      const int row = idx >> 3;                    // [0, 96)
      const int ch  = (idx & 7) ^ (row & 7);
      async16(W + (long)row * DI + kcol + ch * 8,
              &lds[2 * ABUF + p * BBUF + idx * 8]);
    }
  };

  constexpr int NT = DI / 64;   // 32
  stage(0, 0);
  stage(1, 1);
  asm volatile("s_waitcnt vmcnt(%0)" :: "n"(NL) : "memory");
  __builtin_amdgcn_sched_barrier(0);
  __builtin_amdgcn_s_barrier();

  for (int kt = 0; kt < NT; ++kt) {
    const unsigned short* Ab = &lds[(kt & 1) * ABUF];
    const unsigned short* Bb = &lds[2 * ABUF + (kt & 1) * BBUF];
    __builtin_amdgcn_s_setprio(1);
    #pragma unroll
    for (int kk = 0; kk < 2; ++kk) {
      const int ra = wv * 16 + frow;
      const int cha = (kk * 4 + klg) ^ (ra & 7);
      const bfrag a = *reinterpret_cast<const bfrag*>(&Ab[ra * 64 + cha * 8]);
      #pragma unroll
      for (int n = 0; n < 6; ++n) {
        const int rb = n * 16 + frow;
        const int chb = (kk * 4 + klg) ^ (rb & 7);
        const bfrag b = *reinterpret_cast<const bfrag*>(&Bb[rb * 64 + chb * 8]);
        acc[n] = __builtin_amdgcn_mfma_f32_16x16x32_bf16(b, a, acc[n], 0, 0, 0);
      }
    }
    __builtin_amdgcn_s_setprio(0);
    if (kt + 1 == NT) break;
    __builtin_amdgcn_sched_barrier(0);
    __builtin_amdgcn_s_barrier();
    if (kt + 2 < NT) {
      stage(kt + 2, kt & 1);
      asm volatile("s_waitcnt vmcnt(%0)" :: "n"(NL) : "memory");
    } else {
      asm volatile("s_waitcnt vmcnt(0)" ::: "memory");
    }
    __builtin_amdgcn_sched_barrier(0);
    __builtin_amdgcn_s_barrier();
  }

  const long row = bm + wv*16 + frow;
  #pragma unroll
  for (int n = 0; n < 6; ++n) {
    const int col = n*16 + klg*4;
    float4 v; v.x = acc[n][0]; v.y = acc[n][1]; v.z = acc[n][2]; v.w = acc[n][3];
    *reinterpret_cast<float4*>(&xdbl[row * 96 + col]) = v;
    if (n < 4) {
      ushort4 o; o.x = f2b(v.x); o.y = f2b(v.y); o.z = f2b(v.z); o.w = f2b(v.w);
      *reinterpret_cast<ushort4*>(&dtr[row * 64 + col]) = o;
    }
  }
}

// ---------------- fused f32 -> bf16 convert (all 7 segments) ----------------
__global__ __launch_bounds__(256) void cvt_all(
    const float* __restrict__ s0, unsigned short* __restrict__ d0, long n0,
    const float* __restrict__ s1, unsigned short* __restrict__ d1, long n1,
    const float* __restrict__ s2, unsigned short* __restrict__ d2, long n2,
    const float* __restrict__ s3, unsigned short* __restrict__ d3, long n3,
    const float* __restrict__ s4, unsigned short* __restrict__ d4, long n4,
    const float* __restrict__ s5, unsigned short* __restrict__ d5, long n5,
    const float* __restrict__ s6, unsigned short* __restrict__ d6, long n6)
{
  long i = (long)blockIdx.x * 256 + threadIdx.x;
  const float* s; unsigned short* d;
  if      (i < n0)                    { s = s0; d = d0; }
  else if ((i -= n0) < n1)            { s = s1; d = d1; }
  else if ((i -= n1) < n2)            { s = s2; d = d2; }
  else if ((i -= n2) < n3)            { s = s3; d = d3; }
  else if ((i -= n3) < n4)            { s = s4; d = d4; }
  else if ((i -= n4) < n5)            { s = s5; d = d5; }
  else if ((i -= n5) < n6)            { s = s6; d = d6; }
  else return;
  const float4 v = reinterpret_cast<const float4*>(s)[i];
  ushort4 o; o.x = f2b(v.x); o.y = f2b(v.y); o.z = f2b(v.z); o.w = f2b(v.w);
  reinterpret_cast<ushort4*>(d)[i] = o;
}

// ---------------- depthwise causal conv (k=4) + silu, bf16 in/out ----------------
__global__ __launch_bounds__(256) void conv_silu(
    const unsigned short* __restrict__ xin,
    const float* __restrict__ w,     // (DI, 4) f32
    const float* __restrict__ bias,  // (DI) f32
    unsigned short* __restrict__ xc)
{
  const int idx = blockIdx.x * 256 + threadIdx.x;
  const int D4 = DI / 4;
  const int d  = (idx % D4) * 4;
  const int bt = idx / D4;
  const int t  = bt & (L - 1);
  const int b  = bt >> 11;
  const float4 w0 = *reinterpret_cast<const float4*>(w + (long)(d+0)*4);
  const float4 w1 = *reinterpret_cast<const float4*>(w + (long)(d+1)*4);
  const float4 w2 = *reinterpret_cast<const float4*>(w + (long)(d+2)*4);
  const float4 w3 = *reinterpret_cast<const float4*>(w + (long)(d+3)*4);
  const float4 bv = *reinterpret_cast<const float4*>(bias + d);
  float a0 = bv.x, a1 = bv.y, a2 = bv.z, a3 = bv.w;
  const float wk0[4] = {w0.x, w0.y, w0.z, w0.w};
  const float wk1[4] = {w1.x, w1.y, w1.z, w1.w};
  const float wk2[4] = {w2.x, w2.y, w2.z, w2.w};
  const float wk3[4] = {w3.x, w3.y, w3.z, w3.w};
  #pragma unroll
  for (int k = 0; k < 4; ++k) {
    const int tt = t - 3 + k;
    if (tt >= 0) {
      const ushort4 xv = *reinterpret_cast<const ushort4*>(xin + ((long)(b * L + tt)) * DI + d);
      a0 = fmaf(wk0[k], b2f(xv.x), a0);
      a1 = fmaf(wk1[k], b2f(xv.y), a1);
      a2 = fmaf(wk2[k], b2f(xv.z), a2);
      a3 = fmaf(wk3[k], b2f(xv.w), a3);
    }
  }
  a0 = a0 / (1.f + __expf(-a0));
  a1 = a1 / (1.f + __expf(-a1));
  a2 = a2 / (1.f + __expf(-a2));
  a3 = a3 / (1.f + __expf(-a3));
  ushort4 o; o.x = f2b(a0); o.y = f2b(a1); o.z = f2b(a2); o.w = f2b(a3);
  *reinterpret_cast<ushort4*>(xc + (long)bt * DI + d) = o;
}

// ---------------- chunked selective scan (CL=32, bf16 hend, LDS B/C) -----------
// 2048 blocks/scan (2x TLP vs CL=64) to hide the quarter-rate v_exp chain;
// hend stored bf16 (h_init rel err ~0.4%, inside absmax margin).
__global__ __launch_bounds__(256) void scan_p1(
    const unsigned short* __restrict__ dt,   // (ML, DI) bf16
    const unsigned short* __restrict__ u,    // (ML, DI) bf16
    const float* __restrict__ xdbl,          // (ML, 96): B at 64
    const float* __restrict__ a_log,         // (DI, 16)
    unsigned short* __restrict__ hend,       // (Bsz, NCH, 16, DI) bf16
    float* __restrict__ sdt)                 // (Bsz, NCH, DI)
{
  __shared__ float bcs[CL * 16];             // 2 KB: B rows of the chunk
  const int bid = blockIdx.x;
  const int dg = bid & 7;
  const int c  = (bid >> 3) & (NCH - 1);
  const int b  = bid >> 9;                   // 8 dgroups * 64 chunks
  const int tid = threadIdx.x;
  const int d  = dg * 256 + tid;
  const long row0 = (long)b * L + (long)c * CL;

  if (tid < CL * 4) {  // stage B panel: 32 rows x 16 f32 = 128 x async16
    const int row = tid >> 2, q = tid & 3;
    async16(xdbl + (row0 + row) * 96 + 64 + q * 4, (char*)bcs + tid * 16);
  }

  float A2[16];
  #pragma unroll
  for (int q = 0; q < 4; ++q) {
    const float4 al = *reinterpret_cast<const float4*>(a_log + (long)d * 16 + q * 4);
    A2[q*4+0] = -__expf(al.x) * LOG2E; A2[q*4+1] = -__expf(al.y) * LOG2E;
    A2[q*4+2] = -__expf(al.z) * LOG2E; A2[q*4+3] = -__expf(al.w) * LOG2E;
  }
  float h[16];
  #pragma unroll
  for (int s = 0; s < 16; ++s) h[s] = 0.f;
  float s_dt = 0.f;

  float dtv = b2f(dt[row0 * DI + d]);
  float uv  = b2f(u [row0 * DI + d]);
  asm volatile("s_waitcnt vmcnt(0)" ::: "memory");
  __builtin_amdgcn_sched_barrier(0);
  __syncthreads();                          // B panel ready

  for (int t = 0; t < CL; ++t) {
    float dtn = 0.f, un = 0.f;
    if (t + 1 < CL) {
      const long r2 = row0 + t + 1;
      dtn = b2f(dt[r2 * DI + d]);
      un  = b2f(u [r2 * DI + d]);
    }
    const float* bp = &bcs[t * 16];
    s_dt += dtv;
    const float dtu = dtv * uv;
    #pragma unroll
    for (int s = 0; s < 16; ++s)
      h[s] = fmaf(fexp2(dtv * A2[s]), h[s], dtu * bp[s]);
    dtv = dtn; uv = un;
  }
  const long cb = (long)(b * NCH + c);
  #pragma unroll
  for (int s = 0; s < 16; ++s)
    hend[(cb * 16 + s) * DI + d] = f2b(h[s]);
  sdt[cb * DI + d] = s_dt;
}

__global__ __launch_bounds__(256) void scan_p2(
    unsigned short* __restrict__ hend,       // bf16 inout
    const float* __restrict__ sdt,
    const float* __restrict__ a_log)
{
  const long idx = (long)blockIdx.x * 256 + threadIdx.x;
  const int d = idx & (DI - 1);
  const int s = (idx >> 11) & 15;
  const int b = idx >> 15;
  const float A2 = -__expf(a_log[(long)d * 16 + s]) * LOG2E;
  float h = 0.f;
  for (int c = 0; c < NCH; ++c) {
    const long cb = (long)(b * NCH + c);
    const long off = (cb * 16 + s) * DI + d;
    const float hl = b2f(hend[off]);
    const float sd = sdt[cb * DI + d];
    hend[off] = f2b(h);
    h = fmaf(fexp2(A2 * sd), h, hl);
  }
}

__global__ __launch_bounds__(256) void scan_p3(
    const unsigned short* __restrict__ dt,
    const unsigned short* __restrict__ u,
    const float* __restrict__ xdbl,          // B at 64, C at 80
    const unsigned short* __restrict__ z,
    const float* __restrict__ a_log,
    const float* __restrict__ dpar,
    const unsigned short* __restrict__ hinit, // bf16
    unsigned short* __restrict__ y)
{
  __shared__ float bcs[CL * 32];             // 4 KB: B+C rows of the chunk
  const int bid = blockIdx.x;
  const int dg = bid & 7;
  const int c  = (bid >> 3) & (NCH - 1);
  const int b  = bid >> 9;
  const int tid = threadIdx.x;
  const int d  = dg * 256 + tid;
  const long row0 = (long)b * L + (long)c * CL;

  {  // stage B+C panel: 32 rows x 32 f32 = 256 x async16 (1/thread)
    const int row = tid >> 3, q = tid & 7;
    async16(xdbl + (row0 + row) * 96 + 64 + q * 4, (char*)bcs + tid * 16);
  }

  float A2[16];
  #pragma unroll
  for (int q = 0; q < 4; ++q) {
    const float4 al = *reinterpret_cast<const float4*>(a_log + (long)d * 16 + q * 4);
    A2[q*4+0] = -__expf(al.x) * LOG2E; A2[q*4+1] = -__expf(al.y) * LOG2E;
    A2[q*4+2] = -__expf(al.z) * LOG2E; A2[q*4+3] = -__expf(al.w) * LOG2E;
  }
  const float Dv = dpar[d];
  const long cb = (long)(b * NCH + c);
  float h[16];
  #pragma unroll
  for (int s = 0; s < 16; ++s)
    h[s] = b2f(hinit[(cb * 16 + s) * DI + d]);

  float dtv = b2f(dt[row0 * DI + d]);
  float uv  = b2f(u [row0 * DI + d]);
  float zv  = b2f(z [row0 * DI + d]);
  asm volatile("s_waitcnt vmcnt(0)" ::: "memory");
  __builtin_amdgcn_sched_barrier(0);
  __syncthreads();                          // B/C panel ready

  for (int t = 0; t < CL; ++t) {
    float dtn = 0.f, un = 0.f, zn = 0.f;
    if (t + 1 < CL) {
      const long r2 = row0 + t + 1;
      dtn = b2f(dt[r2 * DI + d]);
      un  = b2f(u [r2 * DI + d]);
      zn  = b2f(z [r2 * DI + d]);
    }
    const float* bp = &bcs[t * 32];          // B at +0, C at +16
    const float dtu = dtv * uv;
    float yv = 0.f;
    #pragma unroll
    for (int s = 0; s < 16; ++s) {
      h[s] = fmaf(fexp2(dtv * A2[s]), h[s], dtu * bp[s]);
      yv = fmaf(h[s], bp[16 + s], yv);
    }
    const float sg = zv / (1.f + __expf(-zv));
    y[(row0 + t) * DI + d] = f2b(fmaf(uv, Dv, yv) * sg);
    dtv = dtn; uv = un; zv = zn;
  }
}

// ---------------- fused add-residual + rmsnorm (bf16 chain) ----------------
template<bool RES_F32, bool WRITE_BF, bool WRITE_F32>
__global__ __launch_bounds__(256) void add_rmsnorm(
    const unsigned short* __restrict__ xin,
    const void* __restrict__ resp,
    const float* __restrict__ w,
    unsigned short* __restrict__ out_bf,
    float* __restrict__ out_f32)
{
  const int row = blockIdx.x;
  const int tid = threadIdx.x;
  const long base = (long)row * D;
  const ushort4 t = *reinterpret_cast<const ushort4*>(xin + base + tid * 4);
  float4 v;
  v.x = b2f(t.x); v.y = b2f(t.y); v.z = b2f(t.z); v.w = b2f(t.w);
  if (RES_F32) {
    const float4 r = *reinterpret_cast<const float4*>((const float*)resp + base + tid * 4);
    v.x += r.x; v.y += r.y; v.z += r.z; v.w += r.w;
  } else {
    const ushort4 rb = *reinterpret_cast<const ushort4*>((const unsigned short*)resp + base + tid * 4);
    v.x += b2f(rb.x); v.y += b2f(rb.y); v.z += b2f(rb.z); v.w += b2f(rb.w);
  }
  float ss = v.x*v.x + v.y*v.y + v.z*v.z + v.w*v.w;
  #pragma unroll
  for (int m = 1; m < 64; m <<= 1) ss += __shfl_xor(ss, m);
  __shared__ float red[4];
  if ((tid & 63) == 0) red[tid >> 6] = ss;
  __syncthreads();
  const float tot = red[0] + red[1] + red[2] + red[3];
  const float scale = rsqrtf(tot * (1.f / (float)D) + 1.1920929e-07f);
  const float4 wv = *reinterpret_cast<const float4*>(w + tid * 4);
  float4 o;
  o.x = v.x * scale * wv.x;
  o.y = v.y * scale * wv.y;
  o.z = v.z * scale * wv.z;
  o.w = v.w * scale * wv.w;
  if (WRITE_BF) {
    ushort4 ob; ob.x = f2b(o.x); ob.y = f2b(o.y); ob.z = f2b(o.z); ob.w = f2b(o.w);
    *reinterpret_cast<ushort4*>(out_bf + base + tid * 4) = ob;
  }
  if (WRITE_F32)
    *reinterpret_cast<float4*>(out_f32 + base + tid * 4) = o;
}

} // namespace

extern "C" void kernel_launch(void* const* d_in, const int* in_sizes, int n_in,
                              void* d_out, int out_size, void* d_ws, size_t ws_size,
                              hipStream_t stream)
{
  const float* x0     = (const float*)d_in[0];
  const float* in_w   = (const float*)d_in[1];
  const float* conv_w = (const float*)d_in[2];
  const float* conv_b = (const float*)d_in[3];
  const float* xp_w   = (const float*)d_in[4];
  const float* dtp_w  = (const float*)d_in[5];
  const float* dtp_b  = (const float*)d_in[6];
  const float* a_log  = (const float*)d_in[7];
  const float* d_par  = (const float*)d_in[8];
  const float* out_w  = (const float*)d_in[9];
  const float* w1     = (const float*)d_in[10];
  const float* b1     = (const float*)d_in[11];
  const float* w2     = (const float*)d_in[12];
  const float* b2     = (const float*)d_in[13];
  const float* ln_w   = (const float*)d_in[14];
  const float* ln2_w  = (const float*)d_in[15];
  float* out = (float*)d_out;

  // ---- workspace layout (<= 218 MiB; 224 MiB proven safe in round 2) ----
  char* ws = (char*)d_ws;
  unsigned short* in_wb  = (unsigned short*)(ws);                 // 16 Mi
  unsigned short* out_wb = (unsigned short*)(ws + (16UL  << 20)); //  8 Mi
  unsigned short* w1b    = (unsigned short*)(ws + (24UL  << 20)); //  4 Mi
  unsigned short* w2b    = (unsigned short*)(ws + (28UL  << 20)); //  4 Mi
  unsigned short* xbf    = (unsigned short*)(ws + (32UL  << 20)); // 16 Mi: x chain (bf16)
  unsigned short* zb     = (unsigned short*)(ws + (48UL  << 20)); // 32 Mi
  unsigned short* xc     = (unsigned short*)(ws + (80UL  << 20)); // 32 Mi
  float*          xdbl   = (float*)(ws + (112UL << 20));          //  3 Mi
  unsigned short* hendb  = (unsigned short*)(ws + (115UL << 20)); // 16 Mi (bf16, NCH=64)
  unsigned short* xinb   = (unsigned short*)(ws + (132UL << 20)); // 32 Mi (alias: dt)
  unsigned short* dtb    = xinb;
  unsigned short* ybf    = (unsigned short*)(ws + (164UL << 20)); // 32 Mi (alias: hm)
  unsigned short* hm     = ybf;
  unsigned short* mo     = (unsigned short*)(ws + (196UL << 20)); // 16 Mi (alias: t2)
  unsigned short* t2     = mo;
  unsigned short* xp_wb  = (unsigned short*)(ws + (212UL << 20)); // 0.75 Mi
  unsigned short* dtp_wb = (unsigned short*)(ws + (213UL << 20)); // 0.5 Mi
  unsigned short* dtrb   = (unsigned short*)(ws + (214UL << 20)); // 1 Mi: (ML,64) bf16
  float*          sdtb   = (float*)(ws + (216UL << 20));          // 2 Mi (NCH=64)

  const dim3 blk(256);
  const dim3 blk5(512);

  // one fused f32 -> bf16 conversion (weights + layer-0 input)
  {
    const long n0 = 2L*2*DI*D/4, n1 = 2L*D*DI/4, n2 = 2L*D*D/4, n3 = 2L*D*D/4;
    const long n4 = 2L*96*DI/4,  n5 = 2L*DI*DTR/4, n6 = (long)ML*D/4;
    const long tot = n0+n1+n2+n3+n4+n5+n6;
    cvt_all<<<dim3((tot + 255)/256), blk, 0, stream>>>(
        in_w, in_wb, n0,  out_w, out_wb, n1,  w1, w1b, n2,  w2, w2b, n3,
        xp_w, xp_wb, n4,  dtp_w, dtp_wb, n5,  x0, xbf, n6);
  }

  for (int layer = 0; layer < 2; ++layer) {
    const long lo = (long)layer;
    const unsigned short* Winb = in_wb + lo * 2 * DI * D;
    // 1. [x_in | z] = x @ in_proj^T  (4-phase 256-tile, N=4096, K=1024, split)
    gemm4<0,false,256,true><<<dim3(16, 32), blk5, 0, stream>>>(
        xbf, D, Winb, D, nullptr, xinb, zb, DI, D);
    // 2. xc = silu(causal_conv(x_in))
    conv_silu<<<dim3((long)ML*DI/4/256), blk, 0, stream>>>(
        xinb, conv_w + lo*DI*4, conv_b + lo*DI, xc);
    // 3. xdbl = xc @ x_proj^T  (dbuf MFMA, N=96, K=2048) + bf16 dt cols
    xproj_mfma<<<dim3(ML/64), blk, 0, stream>>>(
        xc, xp_wb + lo*96*DI, xdbl, dtrb);
    // 4. dt = softplus(dtr @ dt_proj^T + b)  (MFMA 128-tile, N=2048, K=64)
    gemm_mfma<3,true><<<dim3(DI/128, ML/128), blk, 0, stream>>>(
        dtrb, DTR, dtp_wb + lo*DI*DTR, DTR, dtp_b + lo*DI, dtb, DI, DTR);
    // 5. chunked selective scan -> ybf bf16  (CL=32: 2048 blocks)
    scan_p1<<<dim3(Bsz*NCH*(DI/256)), blk, 0, stream>>>(
        dtb, xc, xdbl, a_log + lo*DI*DSTATE, hendb, sdtb);
    scan_p2<<<dim3(Bsz*DSTATE*DI/256), blk, 0, stream>>>(
        hendb, sdtb, a_log + lo*DI*DSTATE);
    scan_p3<<<dim3(Bsz*NCH*(DI/256)), blk, 0, stream>>>(
        dtb, xc, xdbl, zb, a_log + lo*DI*DSTATE, d_par + lo*DI, hendb, ybf);
    // 6. mo = y @ out_proj^T  (128x256 2-phase, N=1024, K=2048)
    gemm128<0,false><<<dim3(4, 64), blk5, 0, stream>>>(
        ybf, DI, out_wb + lo*D*DI, DI, nullptr, mo, D, DI);
    // 7. hm = gelu(mo @ w1^T + b1)  (4-phase 256-tile, N=2048, K=1024)
    gemm4<2,true,256,false><<<dim3(8, 32), blk5, 0, stream>>>(
        mo, D, w1b, D, b1, hm, nullptr, 2*D, D);
    // 8. t2 = gelu(hm @ w2^T + b2)  (128x256 2-phase, N=1024, K=2048)
    gemm128<2,true><<<dim3(4, 64), blk5, 0, stream>>>(
        hm, 2*D, w2b, 2*D, b2, t2, D, 2*D);
    // 9. x = rmsnorm(t2 + x) -> xbf (bf16, in-place residual chain)
    add_rmsnorm<false,true,false><<<dim3(ML), blk, 0, stream>>>(
        t2, xbf, ln_w, xbf, nullptr);
  }
  // final: out = rmsnorm(x + x0)  (f32 residual, f32 output)
  add_rmsnorm<true,false,true><<<dim3(ML), blk, 0, stream>>>(
      xbf, x0, ln2_w, nullptr, out);
}

// Round 20
// 899.734 us; speedup vs baseline: 1.0129x; 1.0062x over previous
//
#include <hip/hip_runtime.h>
#include <math.h>

namespace {

constexpr int Bsz = 4;
constexpr int L   = 2048;
constexpr int D   = 1024;
constexpr int DI  = 2048;
constexpr int DSTATE = 16;
constexpr int DTR = 64;
constexpr int ML  = Bsz * L; // 8192 rows
constexpr int NCH = 64;      // chunks per sequence
constexpr int CL  = 32;      // chunk length
constexpr float LOG2E = 1.4426950408889634f;

typedef __attribute__((ext_vector_type(8))) short bfrag;   // 8 bf16 (4 VGPRs)
typedef __attribute__((ext_vector_type(4))) float f32x4;

// ---- bf16 bit helpers (RNE) ----
__device__ __forceinline__ unsigned short f2b(float f) {
  union { float f; unsigned int u; } c; c.f = f;
  unsigned int u = c.u;
  unsigned int r = (u + 0x7fffu + ((u >> 16) & 1u)) >> 16;
  return (unsigned short)r;
}
__device__ __forceinline__ float b2f(unsigned short h) {
  union { unsigned int u; float f; } c; c.u = ((unsigned int)h) << 16;
  return c.f;
}
__device__ __forceinline__ float fexp2(float x) {
  return __builtin_amdgcn_exp2f(x);
}

// ---- async global->LDS 16B ----
__device__ __forceinline__ void async16(const void* g, void* l) {
  __builtin_amdgcn_global_load_lds(
      (const __attribute__((address_space(1))) void*)g,
      (__attribute__((address_space(3))) void*)l, 16, 0, 0);
}

// ---------------- activations (HW-fast transcendentals only) ----------------
template<int ACT>
__device__ __forceinline__ float activate(float x) {
  if (ACT == 1) {                       // silu
    return x / (1.f + __expf(-x));
  }
  if (ACT == 2) {                       // gelu (tanh form, max dev ~3e-3)
    const float y = 1.5957691216f * (x + 0.044715f * x * x * x);
    return x / (1.f + __expf(-y));
  }
  if (ACT == 3) {                       // softplus
    return (x > 20.f) ? x : __logf(1.f + __expf(x));
  }
  return x;
}

// ---------------- 256-tile 4-phase bf16 MFMA GEMM (m201-style sync skeleton) ---
// r20 change vs r13 (ONLY the sync skeleton; identical LDS layout/swizzle,
// vmcnt ledger, fragment reads, epilogue): each phase now ends its read+issue
// region with s_barrier, then lgkmcnt(0) right before the MFMA cluster -> waves
// phase-split into {ds_read||stage-issue} vs {MFMA} roles (the regime where
// setprio pays, per the 8-phase template).
template<int ACT, bool HAS_BIAS, int BN, bool SPLIT>
__global__ __launch_bounds__(512) void gemm4(
    const unsigned short* __restrict__ A, long lda,
    const unsigned short* __restrict__ W, long ldw,
    const float* __restrict__ bias,
    unsigned short* __restrict__ C0,
    unsigned short* __restrict__ C1,
    long ldc, int K)
{
  constexpr int NB   = BN / 64;      // n-frags per wave (4 or 2)
  constexpr int ABUF = 256 * 64;     // elems per A buffer
  constexpr int BBUF = BN * 64;
  constexpr int UB   = NB;           // B-unit loads per thread (4 or 2)
  __shared__ unsigned short lds[2 * ABUF + 2 * BBUF];

  const int tid  = threadIdx.x;
  const int lane = tid & 63;
  const int wid  = tid >> 6;
  const int wr   = wid >> 2;         // 0..1
  const int wc   = wid & 3;          // 0..3
  const int frow = lane & 15;
  const int klg  = lane >> 4;

  // chunked n-major XCD swizzle (nwg % 8 == 0 for all our grids)
  const int gy = gridDim.y;
  int id = blockIdx.x * gy + blockIdx.y;          // hw linear (n-major)
  const int q = (gridDim.x * gy) >> 3;
  id = (id & 7) * q + (id >> 3);                  // XCD k -> contiguous chunk
  const int by = id % gy;
  const int bx = id / gy;
  const long bm = (long)by * 256;
  const long bn = (long)bx * BN;

  unsigned short* Cb;
  long cbase;
  if (SPLIT) {
    if (bn < 2048) { Cb = C0; cbase = bn; }
    else           { Cb = C1; cbase = bn - 2048; }
  } else { Cb = C0; cbase = bn; }

  f32x4 acc[8][NB];
  #pragma unroll
  for (int m = 0; m < 8; ++m)
    #pragma unroll
    for (int n = 0; n < NB; ++n)
      acc[m][n] = (f32x4){0.f, 0.f, 0.f, 0.f};

  auto stageB = [&](int kt) {
    const long kcol = (long)kt * 64;
    unsigned short* dst = &lds[2 * ABUF + (kt & 1) * BBUF];
    #pragma unroll
    for (int l = 0; l < UB; ++l) {
      const int idx = tid + l * 512;               // [0, BN*8)
      const int row = idx >> 3;                    // [0, BN)
      const int ch  = (idx & 7) ^ (row & 7);
      async16(W + (bn + row) * ldw + kcol + ch * 8, dst + idx * 8);
    }
  };
  auto stageA = [&](int kt, int mh) {
    const long kcol = (long)kt * 64;
    unsigned short* dst = &lds[(kt & 1) * ABUF];
    #pragma unroll
    for (int l = 0; l < 2; ++l) {
      const int idx = tid + l * 512;               // [0, 1024)
      const int rl  = idx >> 3;                    // [0, 128)
      const int row = mh * 64 + (rl & 63) + (rl >> 6) * 128;
      const int ch  = (idx & 7) ^ (row & 7);
      async16(A + (bm + row) * lda + kcol + ch * 8, dst + row * 64 + (idx & 7) * 8);
    }
  };

  const int NT = K >> 6;
  stageB(0); stageA(0, 0); stageA(0, 1);
  asm volatile("s_waitcnt vmcnt(%0)" :: "n"(2) : "memory");
  __builtin_amdgcn_sched_barrier(0);
  __builtin_amdgcn_s_barrier();

  for (int kt = 0; kt < NT; ++kt) {
    const unsigned short* Ab = &lds[(kt & 1) * ABUF];
    const unsigned short* Bb = &lds[2 * ABUF + (kt & 1) * BBUF];
    const bool pf = (kt + 1 < NT);
    #pragma unroll
    for (int kk = 0; kk < 2; ++kk) {
      // ---- sub-phase A (mh=0): reads + stage-issue, then barrier+lgkm, MFMA --
      bfrag bv[NB], av[4];
      #pragma unroll
      for (int n = 0; n < NB; ++n) {
        const int r = wc * (BN / 4) + n * 16 + frow;
        bv[n] = *reinterpret_cast<const bfrag*>(&Bb[r * 64 + ((kk * 4 + klg) ^ (r & 7)) * 8]);
      }
      #pragma unroll
      for (int m = 0; m < 4; ++m) {
        const int r = wr * 128 + m * 16 + frow;
        av[m] = *reinterpret_cast<const bfrag*>(&Ab[r * 64 + ((kk * 4 + klg) ^ (r & 7)) * 8]);
      }
      if (pf) { if (kk == 0) stageB(kt + 1); else stageA(kt + 1, 1); }
      __builtin_amdgcn_s_barrier();                     // align roles
      asm volatile("s_waitcnt lgkmcnt(0)" ::: "memory");
      __builtin_amdgcn_sched_barrier(0);
      __builtin_amdgcn_s_setprio(1);
      #pragma unroll
      for (int m = 0; m < 4; ++m)
        #pragma unroll
        for (int n = 0; n < NB; ++n)
          acc[m][n] = __builtin_amdgcn_mfma_f32_16x16x32_bf16(bv[n], av[m], acc[m][n], 0, 0, 0);
      __builtin_amdgcn_s_setprio(0);
      if (kk == 0) {
        asm volatile("s_waitcnt vmcnt(%0)" :: "n"(UB) : "memory");  // A1(t) done
      }
      __builtin_amdgcn_sched_barrier(0);
      __builtin_amdgcn_s_barrier();
      // ---- sub-phase B (mh=1) ----
      #pragma unroll
      for (int m = 0; m < 4; ++m) {
        const int r = wr * 128 + 64 + m * 16 + frow;
        av[m] = *reinterpret_cast<const bfrag*>(&Ab[r * 64 + ((kk * 4 + klg) ^ (r & 7)) * 8]);
      }
      if (pf && kk == 0) stageA(kt + 1, 0);
      __builtin_amdgcn_s_barrier();
      asm volatile("s_waitcnt lgkmcnt(0)" ::: "memory");
      __builtin_amdgcn_sched_barrier(0);
      __builtin_amdgcn_s_setprio(1);
      #pragma unroll
      for (int m = 0; m < 4; ++m)
        #pragma unroll
        for (int n = 0; n < NB; ++n)
          acc[4 + m][n] = __builtin_amdgcn_mfma_f32_16x16x32_bf16(bv[n], av[m], acc[4 + m][n], 0, 0, 0);
      __builtin_amdgcn_s_setprio(0);
      if (kk == 1) {
        if (kt + 1 == NT) break;
        asm volatile("s_waitcnt vmcnt(%0)" :: "n"(2) : "memory");   // B,A0(t+1) done
      }
      __builtin_amdgcn_sched_barrier(0);
      __builtin_amdgcn_s_barrier();
    }
  }

  #pragma unroll
  for (int n = 0; n < NB; ++n) {
    const long coff = wc * (BN / 4) + n * 16 + klg * 4;
    float4 b4 = make_float4(0.f, 0.f, 0.f, 0.f);
    if (HAS_BIAS) b4 = *reinterpret_cast<const float4*>(&bias[bn + coff]);
    #pragma unroll
    for (int m = 0; m < 8; ++m) {
      const long row = bm + wr * 128 + m * 16 + frow;
      const float v0 = activate<ACT>(acc[m][n][0] + b4.x);
      const float v1 = activate<ACT>(acc[m][n][1] + b4.y);
      const float v2 = activate<ACT>(acc[m][n][2] + b4.z);
      const float v3 = activate<ACT>(acc[m][n][3] + b4.w);
      ushort4 o; o.x = f2b(v0); o.y = f2b(v1); o.z = f2b(v2); o.w = f2b(v3);
      *reinterpret_cast<ushort4*>(&Cb[row * ldc + cbase + coff]) = o;
    }
  }
}

// ---------------- 128x256-tile single-barrier bf16 MFMA GEMM (N=1024 ops) ------
template<int ACT, bool HAS_BIAS>
__global__ __launch_bounds__(512) void gemm128(
    const unsigned short* __restrict__ A, long lda,
    const unsigned short* __restrict__ W, long ldw,
    const float* __restrict__ bias,
    unsigned short* __restrict__ C,
    long ldc, int K)
{
  constexpr int ABUF = 128 * 64;     // 16 KB
  constexpr int BBUF = 256 * 64;     // 32 KB
  __shared__ unsigned short lds[2 * ABUF + 2 * BBUF];   // 96 KB

  const int tid  = threadIdx.x;
  const int lane = tid & 63;
  const int wid  = tid >> 6;
  const int wr   = wid >> 2;         // 0..1 (64-row halves)
  const int wc   = wid & 3;          // 0..3 (64-col quarters)
  const int frow = lane & 15;
  const int klg  = lane >> 4;

  const int gy = gridDim.y;
  int id = blockIdx.x * gy + blockIdx.y;
  const int q = (gridDim.x * gy) >> 3;
  id = (id & 7) * q + (id >> 3);
  const int by = id % gy;
  const int bx = id / gy;
  const long bm = (long)by * 128;
  const long bn = (long)bx * 256;

  f32x4 acc[4][4];
  #pragma unroll
  for (int m = 0; m < 4; ++m)
    #pragma unroll
    for (int n = 0; n < 4; ++n)
      acc[m][n] = (f32x4){0.f, 0.f, 0.f, 0.f};

  auto stage = [&](int kt) {
    const long kcol = (long)kt * 64;
    unsigned short* dA = &lds[(kt & 1) * ABUF];
    #pragma unroll
    for (int l = 0; l < 2; ++l) {
      const int idx = tid + l * 512;               // [0, 1024)
      const int row = idx >> 3;                    // [0, 128)
      const int ch  = (idx & 7) ^ (row & 7);
      async16(A + (bm + row) * lda + kcol + ch * 8, dA + idx * 8);
    }
    unsigned short* dB = &lds[2 * ABUF + (kt & 1) * BBUF];
    #pragma unroll
    for (int l = 0; l < 4; ++l) {
      const int idx = tid + l * 512;               // [0, 2048)
      const int row = idx >> 3;                    // [0, 256)
      const int ch  = (idx & 7) ^ (row & 7);
      async16(W + (bn + row) * ldw + kcol + ch * 8, dB + idx * 8);
    }
  };

  const int NT = K >> 6;
  stage(0);
  asm volatile("s_waitcnt vmcnt(0)" ::: "memory");
  __builtin_amdgcn_sched_barrier(0);
  __builtin_amdgcn_s_barrier();

  for (int kt = 0; kt < NT; ++kt) {
    if (kt + 1 < NT) stage(kt + 1);
    __builtin_amdgcn_sched_barrier(0);
    const unsigned short* Ab = &lds[(kt & 1) * ABUF];
    const unsigned short* Bb = &lds[2 * ABUF + (kt & 1) * BBUF];
    __builtin_amdgcn_s_setprio(1);
    #pragma unroll
    for (int kk = 0; kk < 2; ++kk) {
      bfrag av[4], bv[4];
      #pragma unroll
      for (int m = 0; m < 4; ++m) {
        const int r = wr * 64 + m * 16 + frow;
        av[m] = *reinterpret_cast<const bfrag*>(&Ab[r * 64 + ((kk * 4 + klg) ^ (r & 7)) * 8]);
      }
      #pragma unroll
      for (int n = 0; n < 4; ++n) {
        const int r = wc * 64 + n * 16 + frow;
        bv[n] = *reinterpret_cast<const bfrag*>(&Bb[r * 64 + ((kk * 4 + klg) ^ (r & 7)) * 8]);
      }
      #pragma unroll
      for (int m = 0; m < 4; ++m)
        #pragma unroll
        for (int n = 0; n < 4; ++n)
          acc[m][n] = __builtin_amdgcn_mfma_f32_16x16x32_bf16(bv[n], av[m], acc[m][n], 0, 0, 0);
    }
    __builtin_amdgcn_s_setprio(0);
    if (kt + 1 == NT) break;
    asm volatile("s_waitcnt vmcnt(0)" ::: "memory");
    __builtin_amdgcn_sched_barrier(0);
    __builtin_amdgcn_s_barrier();
  }

  #pragma unroll
  for (int n = 0; n < 4; ++n) {
    const long coff = bn + wc * 64 + n * 16 + klg * 4;
    float4 b4 = make_float4(0.f, 0.f, 0.f, 0.f);
    if (HAS_BIAS) b4 = *reinterpret_cast<const float4*>(&bias[coff]);
    #pragma unroll
    for (int m = 0; m < 4; ++m) {
      const long row = bm + wr * 64 + m * 16 + frow;
      const float v0 = activate<ACT>(acc[m][n][0] + b4.x);
      const float v1 = activate<ACT>(acc[m][n][1] + b4.y);
      const float v2 = activate<ACT>(acc[m][n][2] + b4.z);
      const float v3 = activate<ACT>(acc[m][n][3] + b4.w);
      ushort4 o; o.x = f2b(v0); o.y = f2b(v1); o.z = f2b(v2); o.w = f2b(v3);
      *reinterpret_cast<ushort4*>(&C[row * ldc + coff]) = o;
    }
  }
}

// ---------------- 128-tile MFMA GEMM (dt_proj: K=64, write-bound) ----------------
template<int ACT, bool HAS_BIAS>
__global__ __launch_bounds__(256) void gemm_mfma(
    const unsigned short* __restrict__ A, long lda,
    const unsigned short* __restrict__ W, long ldw,
    const float* __restrict__ bias,
    unsigned short* __restrict__ C, long ldc,
    int K)
{
  __shared__ unsigned short As[128 * 32];
  __shared__ unsigned short Bs[128 * 32];
  const int tid  = threadIdx.x;
  const int lane = tid & 63;
  const int w    = tid >> 6;
  const int wr   = w >> 1, wc = w & 1;
  const long bm = (long)blockIdx.y * 128;
  const long bn = (long)blockIdx.x * 128;

  const int srow = tid >> 2;
  const int scol = (tid & 3) * 8;
  const unsigned short* ga0 = A + (bm + srow)      * lda + scol;
  const unsigned short* ga1 = A + (bm + 64 + srow) * lda + scol;
  const unsigned short* gb0 = W + (bn + srow)      * ldw + scol;
  const unsigned short* gb1 = W + (bn + 64 + srow) * ldw + scol;
  char* lA = (char*)As;
  char* lB = (char*)Bs;
  const int loff = tid * 16;

  const int frow = lane & 15;
  const int klg  = lane >> 4;
  const int fko  = klg * 8;

  f32x4 acc[4][4];
  #pragma unroll
  for (int m = 0; m < 4; ++m)
    #pragma unroll
    for (int n = 0; n < 4; ++n)
      acc[m][n] = (f32x4){0.f, 0.f, 0.f, 0.f};

  for (int k0 = 0; k0 < K; k0 += 32) {
    __syncthreads();
    async16(ga0 + k0, lA + loff);
    async16(ga1 + k0, lA + 4096 + loff);
    async16(gb0 + k0, lB + loff);
    async16(gb1 + k0, lB + 4096 + loff);
    __syncthreads();
    bfrag a[4], b[4];
    #pragma unroll
    for (int m = 0; m < 4; ++m)
      a[m] = *reinterpret_cast<const bfrag*>(&As[(wr*64 + m*16 + frow)*32 + fko]);
    #pragma unroll
    for (int n = 0; n < 4; ++n)
      b[n] = *reinterpret_cast<const bfrag*>(&Bs[(wc*64 + n*16 + frow)*32 + fko]);
    #pragma unroll
    for (int m = 0; m < 4; ++m)
      #pragma unroll
      for (int n = 0; n < 4; ++n)
        acc[m][n] = __builtin_amdgcn_mfma_f32_16x16x32_bf16(b[n], a[m], acc[m][n], 0, 0, 0);
  }

  #pragma unroll
  for (int n = 0; n < 4; ++n) {
    const long col = bn + wc*64 + n*16 + klg*4;
    float4 b4 = make_float4(0.f, 0.f, 0.f, 0.f);
    if (HAS_BIAS) b4 = *reinterpret_cast<const float4*>(&bias[col]);
    #pragma unroll
    for (int m = 0; m < 4; ++m) {
      const long row = bm + wr*64 + m*16 + frow;
      const float v0 = activate<ACT>(acc[m][n][0] + b4.x);
      const float v1 = activate<ACT>(acc[m][n][1] + b4.y);
      const float v2 = activate<ACT>(acc[m][n][2] + b4.z);
      const float v3 = activate<ACT>(acc[m][n][3] + b4.w);
      ushort4 o; o.x = f2b(v0); o.y = f2b(v1); o.z = f2b(v2); o.w = f2b(v3);
      *reinterpret_cast<ushort4*>(&C[row * ldc + col]) = o;
    }
  }
}

// ---------------- x_proj MFMA (double-buffered, counted vmcnt) ----------------
__global__ __launch_bounds__(256) void xproj_mfma(
    const unsigned short* __restrict__ A,   // xc (ML x DI)
    const unsigned short* __restrict__ W,   // xp_wb (96 x DI)
    float* __restrict__ xdbl,               // (ML x 96) f32
    unsigned short* __restrict__ dtr)       // (ML x 64) bf16
{
  constexpr int ABUF = 64 * 64;    // 8 KiB
  constexpr int BBUF = 96 * 64;    // 12 KiB
  constexpr int NL   = 5;          // 2 A-loads + 3 B-loads per thread
  __shared__ unsigned short lds[2 * ABUF + 2 * BBUF];  // 40 KiB

  const int tid  = threadIdx.x;
  const int lane = tid & 63;
  const int wv   = tid >> 6;
  const int frow = lane & 15;
  const int klg  = lane >> 4;
  const long bm  = (long)blockIdx.x * 64;

  f32x4 acc[6];
  #pragma unroll
  for (int n = 0; n < 6; ++n) acc[n] = (f32x4){0.f, 0.f, 0.f, 0.f};

  auto stage = [&](int kt, int p) {
    const long kcol = (long)kt * 64;
    #pragma unroll
    for (int l = 0; l < 2; ++l) {
      const int idx = tid + l * 256;
      const int row = idx >> 3;                    // [0, 64)
      const int ch  = (idx & 7) ^ (row & 7);
      async16(A + (bm + row) * DI + kcol + ch * 8,
              &lds[p * ABUF + idx * 8]);
    }
    #pragma unroll
    for (int l = 0; l < 3; ++l) {
      const int idx = tid + l * 256;
      const int row = idx >> 3;                    // [0, 96)
      const int ch  = (idx & 7) ^ (row & 7);
      async16(W + (long)row * DI + kcol + ch * 8,
              &lds[2 * ABUF + p * BBUF + idx * 8]);
    }
  };

  constexpr int NT = DI / 64;   // 32
  stage(0, 0);
  stage(1, 1);
  asm volatile("s_waitcnt vmcnt(%0)" :: "n"(NL) : "memory");
  __builtin_amdgcn_sched_barrier(0);
  __builtin_amdgcn_s_barrier();

  for (int kt = 0; kt < NT; ++kt) {
    const unsigned short* Ab = &lds[(kt & 1) * ABUF];
    const unsigned short* Bb = &lds[2 * ABUF + (kt & 1) * BBUF];
    __builtin_amdgcn_s_setprio(1);
    #pragma unroll
    for (int kk = 0; kk < 2; ++kk) {
      const int ra = wv * 16 + frow;
      const int cha = (kk * 4 + klg) ^ (ra & 7);
      const bfrag a = *reinterpret_cast<const bfrag*>(&Ab[ra * 64 + cha * 8]);
      #pragma unroll
      for (int n = 0; n < 6; ++n) {
        const int rb = n * 16 + frow;
        const int chb = (kk * 4 + klg) ^ (rb & 7);
        const bfrag b = *reinterpret_cast<const bfrag*>(&Bb[rb * 64 + chb * 8]);
        acc[n] = __builtin_amdgcn_mfma_f32_16x16x32_bf16(b, a, acc[n], 0, 0, 0);
      }
    }
    __builtin_amdgcn_s_setprio(0);
    if (kt + 1 == NT) break;
    __builtin_amdgcn_sched_barrier(0);
    __builtin_amdgcn_s_barrier();
    if (kt + 2 < NT) {
      stage(kt + 2, kt & 1);
      asm volatile("s_waitcnt vmcnt(%0)" :: "n"(NL) : "memory");
    } else {
      asm volatile("s_waitcnt vmcnt(0)" ::: "memory");
    }
    __builtin_amdgcn_sched_barrier(0);
    __builtin_amdgcn_s_barrier();
  }

  const long row = bm + wv*16 + frow;
  #pragma unroll
  for (int n = 0; n < 6; ++n) {
    const int col = n*16 + klg*4;
    float4 v; v.x = acc[n][0]; v.y = acc[n][1]; v.z = acc[n][2]; v.w = acc[n][3];
    *reinterpret_cast<float4*>(&xdbl[row * 96 + col]) = v;
    if (n < 4) {
      ushort4 o; o.x = f2b(v.x); o.y = f2b(v.y); o.z = f2b(v.z); o.w = f2b(v.w);
      *reinterpret_cast<ushort4*>(&dtr[row * 64 + col]) = o;
    }
  }
}

// ---------------- fused f32 -> bf16 convert (all 7 segments) ----------------
__global__ __launch_bounds__(256) void cvt_all(
    const float* __restrict__ s0, unsigned short* __restrict__ d0, long n0,
    const float* __restrict__ s1, unsigned short* __restrict__ d1, long n1,
    const float* __restrict__ s2, unsigned short* __restrict__ d2, long n2,
    const float* __restrict__ s3, unsigned short* __restrict__ d3, long n3,
    const float* __restrict__ s4, unsigned short* __restrict__ d4, long n4,
    const float* __restrict__ s5, unsigned short* __restrict__ d5, long n5,
    const float* __restrict__ s6, unsigned short* __restrict__ d6, long n6)
{
  long i = (long)blockIdx.x * 256 + threadIdx.x;
  const float* s; unsigned short* d;
  if      (i < n0)                    { s = s0; d = d0; }
  else if ((i -= n0) < n1)            { s = s1; d = d1; }
  else if ((i -= n1) < n2)            { s = s2; d = d2; }
  else if ((i -= n2) < n3)            { s = s3; d = d3; }
  else if ((i -= n3) < n4)            { s = s4; d = d4; }
  else if ((i -= n4) < n5)            { s = s5; d = d5; }
  else if ((i -= n5) < n6)            { s = s6; d = d6; }
  else return;
  const float4 v = reinterpret_cast<const float4*>(s)[i];
  ushort4 o; o.x = f2b(v.x); o.y = f2b(v.y); o.z = f2b(v.z); o.w = f2b(v.w);
  reinterpret_cast<ushort4*>(d)[i] = o;
}

// ---------------- depthwise causal conv (k=4) + silu, bf16 in/out ----------------
__global__ __launch_bounds__(256) void conv_silu(
    const unsigned short* __restrict__ xin,
    const float* __restrict__ w,     // (DI, 4) f32
    const float* __restrict__ bias,  // (DI) f32
    unsigned short* __restrict__ xc)
{
  const int idx = blockIdx.x * 256 + threadIdx.x;
  const int D4 = DI / 4;
  const int d  = (idx % D4) * 4;
  const int bt = idx / D4;
  const int t  = bt & (L - 1);
  const int b  = bt >> 11;
  const float4 w0 = *reinterpret_cast<const float4*>(w + (long)(d+0)*4);
  const float4 w1 = *reinterpret_cast<const float4*>(w + (long)(d+1)*4);
  const float4 w2 = *reinterpret_cast<const float4*>(w + (long)(d+2)*4);
  const float4 w3 = *reinterpret_cast<const float4*>(w + (long)(d+3)*4);
  const float4 bv = *reinterpret_cast<const float4*>(bias + d);
  float a0 = bv.x, a1 = bv.y, a2 = bv.z, a3 = bv.w;
  const float wk0[4] = {w0.x, w0.y, w0.z, w0.w};
  const float wk1[4] = {w1.x, w1.y, w1.z, w1.w};
  const float wk2[4] = {w2.x, w2.y, w2.z, w2.w};
  const float wk3[4] = {w3.x, w3.y, w3.z, w3.w};
  #pragma unroll
  for (int k = 0; k < 4; ++k) {
    const int tt = t - 3 + k;
    if (tt >= 0) {
      const ushort4 xv = *reinterpret_cast<const ushort4*>(xin + ((long)(b * L + tt)) * DI + d);
      a0 = fmaf(wk0[k], b2f(xv.x), a0);
      a1 = fmaf(wk1[k], b2f(xv.y), a1);
      a2 = fmaf(wk2[k], b2f(xv.z), a2);
      a3 = fmaf(wk3[k], b2f(xv.w), a3);
    }
  }
  a0 = a0 / (1.f + __expf(-a0));
  a1 = a1 / (1.f + __expf(-a1));
  a2 = a2 / (1.f + __expf(-a2));
  a3 = a3 / (1.f + __expf(-a3));
  ushort4 o; o.x = f2b(a0); o.y = f2b(a1); o.z = f2b(a2); o.w = f2b(a3);
  *reinterpret_cast<ushort4*>(xc + (long)bt * DI + d) = o;
}

// ---------------- chunked selective scan (CL=32, bf16 hend, LDS B/C) -----------
__global__ __launch_bounds__(256) void scan_p1(
    const unsigned short* __restrict__ dt,   // (ML, DI) bf16
    const unsigned short* __restrict__ u,    // (ML, DI) bf16
    const float* __restrict__ xdbl,          // (ML, 96): B at 64
    const float* __restrict__ a_log,         // (DI, 16)
    unsigned short* __restrict__ hend,       // (Bsz, NCH, 16, DI) bf16
    float* __restrict__ sdt)                 // (Bsz, NCH, DI)
{
  __shared__ float bcs[CL * 16];             // 2 KB: B rows of the chunk
  const int bid = blockIdx.x;
  const int dg = bid & 7;
  const int c  = (bid >> 3) & (NCH - 1);
  const int b  = bid >> 9;                   // 8 dgroups * 64 chunks
  const int tid = threadIdx.x;
  const int d  = dg * 256 + tid;
  const long row0 = (long)b * L + (long)c * CL;

  if (tid < CL * 4) {  // stage B panel: 32 rows x 16 f32 = 128 x async16
    const int row = tid >> 2, q = tid & 3;
    async16(xdbl + (row0 + row) * 96 + 64 + q * 4, (char*)bcs + tid * 16);
  }

  float A2[16];
  #pragma unroll
  for (int q = 0; q < 4; ++q) {
    const float4 al = *reinterpret_cast<const float4*>(a_log + (long)d * 16 + q * 4);
    A2[q*4+0] = -__expf(al.x) * LOG2E; A2[q*4+1] = -__expf(al.y) * LOG2E;
    A2[q*4+2] = -__expf(al.z) * LOG2E; A2[q*4+3] = -__expf(al.w) * LOG2E;
  }
  float h[16];
  #pragma unroll
  for (int s = 0; s < 16; ++s) h[s] = 0.f;
  float s_dt = 0.f;

  float dtv = b2f(dt[row0 * DI + d]);
  float uv  = b2f(u [row0 * DI + d]);
  asm volatile("s_waitcnt vmcnt(0)" ::: "memory");
  __builtin_amdgcn_sched_barrier(0);
  __syncthreads();                          // B panel ready

  for (int t = 0; t < CL; ++t) {
    float dtn = 0.f, un = 0.f;
    if (t + 1 < CL) {
      const long r2 = row0 + t + 1;
      dtn = b2f(dt[r2 * DI + d]);
      un  = b2f(u [r2 * DI + d]);
    }
    const float* bp = &bcs[t * 16];
    s_dt += dtv;
    const float dtu = dtv * uv;
    #pragma unroll
    for (int s = 0; s < 16; ++s)
      h[s] = fmaf(fexp2(dtv * A2[s]), h[s], dtu * bp[s]);
    dtv = dtn; uv = un;
  }
  const long cb = (long)(b * NCH + c);
  #pragma unroll
  for (int s = 0; s < 16; ++s)
    hend[(cb * 16 + s) * DI + d] = f2b(h[s]);
  sdt[cb * DI + d] = s_dt;
}

__global__ __launch_bounds__(256) void scan_p2(
    unsigned short* __restrict__ hend,       // bf16 inout
    const float* __restrict__ sdt,
    const float* __restrict__ a_log)
{
  const long idx = (long)blockIdx.x * 256 + threadIdx.x;
  const int d = idx & (DI - 1);
  const int s = (idx >> 11) & 15;
  const int b = idx >> 15;
  const float A2 = -__expf(a_log[(long)d * 16 + s]) * LOG2E;
  float h = 0.f;
  for (int c = 0; c < NCH; ++c) {
    const long cb = (long)(b * NCH + c);
    const long off = (cb * 16 + s) * DI + d;
    const float hl = b2f(hend[off]);
    const float sd = sdt[cb * DI + d];
    hend[off] = f2b(h);
    h = fmaf(fexp2(A2 * sd), h, hl);
  }
}

__global__ __launch_bounds__(256) void scan_p3(
    const unsigned short* __restrict__ dt,
    const unsigned short* __restrict__ u,
    const float* __restrict__ xdbl,          // B at 64, C at 80
    const unsigned short* __restrict__ z,
    const float* __restrict__ a_log,
    const float* __restrict__ dpar,
    const unsigned short* __restrict__ hinit, // bf16
    unsigned short* __restrict__ y)
{
  __shared__ float bcs[CL * 32];             // 4 KB: B+C rows of the chunk
  const int bid = blockIdx.x;
  const int dg = bid & 7;
  const int c  = (bid >> 3) & (NCH - 1);
  const int b  = bid >> 9;
  const int tid = threadIdx.x;
  const int d  = dg * 256 + tid;
  const long row0 = (long)b * L + (long)c * CL;

  {  // stage B+C panel: 32 rows x 32 f32 = 256 x async16 (1/thread)
    const int row = tid >> 3, q = tid & 7;
    async16(xdbl + (row0 + row) * 96 + 64 + q * 4, (char*)bcs + tid * 16);
  }

  float A2[16];
  #pragma unroll
  for (int q = 0; q < 4; ++q) {
    const float4 al = *reinterpret_cast<const float4*>(a_log + (long)d * 16 + q * 4);
    A2[q*4+0] = -__expf(al.x) * LOG2E; A2[q*4+1] = -__expf(al.y) * LOG2E;
    A2[q*4+2] = -__expf(al.z) * LOG2E; A2[q*4+3] = -__expf(al.w) * LOG2E;
  }
  const float Dv = dpar[d];
  const long cb = (long)(b * NCH + c);
  float h[16];
  #pragma unroll
  for (int s = 0; s < 16; ++s)
    h[s] = b2f(hinit[(cb * 16 + s) * DI + d]);

  float dtv = b2f(dt[row0 * DI + d]);
  float uv  = b2f(u [row0 * DI + d]);
  float zv  = b2f(z [row0 * DI + d]);
  asm volatile("s_waitcnt vmcnt(0)" ::: "memory");
  __builtin_amdgcn_sched_barrier(0);
  __syncthreads();                          // B/C panel ready

  for (int t = 0; t < CL; ++t) {
    float dtn = 0.f, un = 0.f, zn = 0.f;
    if (t + 1 < CL) {
      const long r2 = row0 + t + 1;
      dtn = b2f(dt[r2 * DI + d]);
      un  = b2f(u [r2 * DI + d]);
      zn  = b2f(z [r2 * DI + d]);
    }
    const float* bp = &bcs[t * 32];          // B at +0, C at +16
    const float dtu = dtv * uv;
    float yv = 0.f;
    #pragma unroll
    for (int s = 0; s < 16; ++s) {
      h[s] = fmaf(fexp2(dtv * A2[s]), h[s], dtu * bp[s]);
      yv = fmaf(h[s], bp[16 + s], yv);
    }
    const float sg = zv / (1.f + __expf(-zv));
    y[(row0 + t) * DI + d] = f2b(fmaf(uv, Dv, yv) * sg);
    dtv = dtn; uv = un; zv = zn;
  }
}

// ---------------- fused add-residual + rmsnorm (bf16 chain) ----------------
template<bool RES_F32, bool WRITE_BF, bool WRITE_F32>
__global__ __launch_bounds__(256) void add_rmsnorm(
    const unsigned short* __restrict__ xin,
    const void* __restrict__ resp,
    const float* __restrict__ w,
    unsigned short* __restrict__ out_bf,
    float* __restrict__ out_f32)
{
  const int row = blockIdx.x;
  const int tid = threadIdx.x;
  const long base = (long)row * D;
  const ushort4 t = *reinterpret_cast<const ushort4*>(xin + base + tid * 4);
  float4 v;
  v.x = b2f(t.x); v.y = b2f(t.y); v.z = b2f(t.z); v.w = b2f(t.w);
  if (RES_F32) {
    const float4 r = *reinterpret_cast<const float4*>((const float*)resp + base + tid * 4);
    v.x += r.x; v.y += r.y; v.z += r.z; v.w += r.w;
  } else {
    const ushort4 rb = *reinterpret_cast<const ushort4*>((const unsigned short*)resp + base + tid * 4);
    v.x += b2f(rb.x); v.y += b2f(rb.y); v.z += b2f(rb.z); v.w += b2f(rb.w);
  }
  float ss = v.x*v.x + v.y*v.y + v.z*v.z + v.w*v.w;
  #pragma unroll
  for (int m = 1; m < 64; m <<= 1) ss += __shfl_xor(ss, m);
  __shared__ float red[4];
  if ((tid & 63) == 0) red[tid >> 6] = ss;
  __syncthreads();
  const float tot = red[0] + red[1] + red[2] + red[3];
  const float scale = rsqrtf(tot * (1.f / (float)D) + 1.1920929e-07f);
  const float4 wv = *reinterpret_cast<const float4*>(w + tid * 4);
  float4 o;
  o.x = v.x * scale * wv.x;
  o.y = v.y * scale * wv.y;
  o.z = v.z * scale * wv.z;
  o.w = v.w * scale * wv.w;
  if (WRITE_BF) {
    ushort4 ob; ob.x = f2b(o.x); ob.y = f2b(o.y); ob.z = f2b(o.z); ob.w = f2b(o.w);
    *reinterpret_cast<ushort4*>(out_bf + base + tid * 4) = ob;
  }
  if (WRITE_F32)
    *reinterpret_cast<float4*>(out_f32 + base + tid * 4) = o;
}

} // namespace

extern "C" void kernel_launch(void* const* d_in, const int* in_sizes, int n_in,
                              void* d_out, int out_size, void* d_ws, size_t ws_size,
                              hipStream_t stream)
{
  const float* x0     = (const float*)d_in[0];
  const float* in_w   = (const float*)d_in[1];
  const float* conv_w = (const float*)d_in[2];
  const float* conv_b = (const float*)d_in[3];
  const float* xp_w   = (const float*)d_in[4];
  const float* dtp_w  = (const float*)d_in[5];
  const float* dtp_b  = (const float*)d_in[6];
  const float* a_log  = (const float*)d_in[7];
  const float* d_par  = (const float*)d_in[8];
  const float* out_w  = (const float*)d_in[9];
  const float* w1     = (const float*)d_in[10];
  const float* b1     = (const float*)d_in[11];
  const float* w2     = (const float*)d_in[12];
  const float* b2     = (const float*)d_in[13];
  const float* ln_w   = (const float*)d_in[14];
  const float* ln2_w  = (const float*)d_in[15];
  float* out = (float*)d_out;

  // ---- workspace layout (<= 218 MiB; 224 MiB proven safe) ----
  char* ws = (char*)d_ws;
  unsigned short* in_wb  = (unsigned short*)(ws);                 // 16 Mi
  unsigned short* out_wb = (unsigned short*)(ws + (16UL  << 20)); //  8 Mi
  unsigned short* w1b    = (unsigned short*)(ws + (24UL  << 20)); //  4 Mi
  unsigned short* w2b    = (unsigned short*)(ws + (28UL  << 20)); //  4 Mi
  unsigned short* xbf    = (unsigned short*)(ws + (32UL  << 20)); // 16 Mi: x chain (bf16)
  unsigned short* zb     = (unsigned short*)(ws + (48UL  << 20)); // 32 Mi
  unsigned short* xc     = (unsigned short*)(ws + (80UL  << 20)); // 32 Mi
  float*          xdbl   = (float*)(ws + (112UL << 20));          //  3 Mi
  unsigned short* hendb  = (unsigned short*)(ws + (115UL << 20)); // 16 Mi (bf16, NCH=64)
  unsigned short* xinb   = (unsigned short*)(ws + (132UL << 20)); // 32 Mi (alias: dt)
  unsigned short* dtb    = xinb;
  unsigned short* ybf    = (unsigned short*)(ws + (164UL << 20)); // 32 Mi (alias: hm)
  unsigned short* hm     = ybf;
  unsigned short* mo     = (unsigned short*)(ws + (196UL << 20)); // 16 Mi (alias: t2)
  unsigned short* t2     = mo;
  unsigned short* xp_wb  = (unsigned short*)(ws + (212UL << 20)); // 0.75 Mi
  unsigned short* dtp_wb = (unsigned short*)(ws + (213UL << 20)); // 0.5 Mi
  unsigned short* dtrb   = (unsigned short*)(ws + (214UL << 20)); // 1 Mi: (ML,64) bf16
  float*          sdtb   = (float*)(ws + (216UL << 20));          // 2 Mi (NCH=64)

  const dim3 blk(256);
  const dim3 blk5(512);

  // one fused f32 -> bf16 conversion (weights + layer-0 input)
  {
    const long n0 = 2L*2*DI*D/4, n1 = 2L*D*DI/4, n2 = 2L*D*D/4, n3 = 2L*D*D/4;
    const long n4 = 2L*96*DI/4,  n5 = 2L*DI*DTR/4, n6 = (long)ML*D/4;
    const long tot = n0+n1+n2+n3+n4+n5+n6;
    cvt_all<<<dim3((tot + 255)/256), blk, 0, stream>>>(
        in_w, in_wb, n0,  out_w, out_wb, n1,  w1, w1b, n2,  w2, w2b, n3,
        xp_w, xp_wb, n4,  dtp_w, dtp_wb, n5,  x0, xbf, n6);
  }

  for (int layer = 0; layer < 2; ++layer) {
    const long lo = (long)layer;
    const unsigned short* Winb = in_wb + lo * 2 * DI * D;
    // 1. [x_in | z] = x @ in_proj^T  (4-phase 256-tile, N=4096, K=1024, split)
    gemm4<0,false,256,true><<<dim3(16, 32), blk5, 0, stream>>>(
        xbf, D, Winb, D, nullptr, xinb, zb, DI, D);
    // 2. xc = silu(causal_conv(x_in))
    conv_silu<<<dim3((long)ML*DI/4/256), blk, 0, stream>>>(
        xinb, conv_w + lo*DI*4, conv_b + lo*DI, xc);
    // 3. xdbl = xc @ x_proj^T  (dbuf MFMA, N=96, K=2048) + bf16 dt cols
    xproj_mfma<<<dim3(ML/64), blk, 0, stream>>>(
        xc, xp_wb + lo*96*DI, xdbl, dtrb);
    // 4. dt = softplus(dtr @ dt_proj^T + b)  (MFMA 128-tile, N=2048, K=64)
    gemm_mfma<3,true><<<dim3(DI/128, ML/128), blk, 0, stream>>>(
        dtrb, DTR, dtp_wb + lo*DI*DTR, DTR, dtp_b + lo*DI, dtb, DI, DTR);
    // 5. chunked selective scan -> ybf bf16  (CL=32: 2048 blocks)
    scan_p1<<<dim3(Bsz*NCH*(DI/256)), blk, 0, stream>>>(
        dtb, xc, xdbl, a_log + lo*DI*DSTATE, hendb, sdtb);
    scan_p2<<<dim3(Bsz*DSTATE*DI/256), blk, 0, stream>>>(
        hendb, sdtb, a_log + lo*DI*DSTATE);
    scan_p3<<<dim3(Bsz*NCH*(DI/256)), blk, 0, stream>>>(
        dtb, xc, xdbl, zb, a_log + lo*DI*DSTATE, d_par + lo*DI, hendb, ybf);
    // 6. mo = y @ out_proj^T  (128x256 2-phase, N=1024, K=2048)
    gemm128<0,false><<<dim3(4, 64), blk5, 0, stream>>>(
        ybf, DI, out_wb + lo*D*DI, DI, nullptr, mo, D, DI);
    // 7. hm = gelu(mo @ w1^T + b1)  (4-phase 256-tile, N=2048, K=1024)
    gemm4<2,true,256,false><<<dim3(8, 32), blk5, 0, stream>>>(
        mo, D, w1b, D, b1, hm, nullptr, 2*D, D);
    // 8. t2 = gelu(hm @ w2^T + b2)  (128x256 2-phase, N=1024, K=2048)
    gemm128<2,true><<<dim3(4, 64), blk5, 0, stream>>>(
        hm, 2*D, w2b, 2*D, b2, t2, D, 2*D);
    // 9. x = rmsnorm(t2 + x) -> xbf (bf16, in-place residual chain)
    add_rmsnorm<false,true,false><<<dim3(ML), blk, 0, stream>>>(
        t2, xbf, ln_w, xbf, nullptr);
  }
  // final: out = rmsnorm(x + x0)  (f32 residual, f32 output)
  add_rmsnorm<true,false,true><<<dim3(ML), blk, 0, stream>>>(
      xbf, x0, ln2_w, nullptr, out);
}